// Round 7
// baseline (804.869 us; speedup 1.0000x reference)
//
#include <hip/hip_runtime.h>
#include <hip/hip_bf16.h>

#define DEV __device__ __forceinline__

constexpr int B = 64, D = 256, L = 2048, H = 512, KP = 128;
constexpr float EPS_LN = 1e-6f, EPS_STAT = 1e-10f, EPS_BN = 1e-5f;
constexpr float SCALE = 0.088388347648318447f; // 1/sqrt(128)

typedef __attribute__((ext_vector_type(8))) short short8;
typedef __attribute__((ext_vector_type(4))) float float4_;
typedef __attribute__((ext_vector_type(2))) float float2_;
typedef __attribute__((ext_vector_type(16))) float f32x16;

DEV unsigned short f2bf(float x) {
  unsigned u = __builtin_bit_cast(unsigned, x);
  u += 0x7fffu + ((u >> 16) & 1u);           // RNE
  return (unsigned short)(u >> 16);
}

DEV unsigned pk2bf(float a, float b) {       // two RNE cvts packed into a dword
  return (unsigned)f2bf(a) | ((unsigned)f2bf(b) << 16);
}

DEV float wred(float x) {
  #pragma unroll
  for (int o = 32; o > 0; o >>= 1) x += __shfl_down(x, o, 64);
  return x;
}
DEV float wredmax(float x) {
  #pragma unroll
  for (int o = 32; o > 0; o >>= 1) x = fmaxf(x, __shfl_down(x, o, 64));
  return x;
}

// ---- convert w1/w2 (both layers) to bf16 ----
__global__ void k_convw(const float* __restrict__ w1, const float* __restrict__ w2,
                        unsigned short* __restrict__ w1b, unsigned short* __restrict__ w2b) {
  int n = 2 * H * D;
  for (int i = blockIdx.x * blockDim.x + threadIdx.x; i < n; i += gridDim.x * blockDim.x) {
    w1b[i] = f2bf(w1[i]);
    w2b[i] = f2bf(w2[i]);
  }
}

// ---- P1: fused token-LN stats (m,r) + per-(b,d,tile) partial sums of u,u^2 ----
__global__ __launch_bounds__(512, 4) void k_pass1(
    const float* __restrict__ v, float* __restrict__ m, float* __restrict__ r,
    float* __restrict__ S1p, float* __restrict__ S2p) {
  __shared__ float ut[256 * 65];            // u (fp32), row d stride 65 (pad); front 16KB = parts
  __shared__ float mu_s[64], rs_s[64];
  float* part1 = ut;                        // [32][64] floats = 8KB (dead before ut written)
  float* part2 = ut + 2048;                 // [32][64]

  int blk = blockIdx.x;
  int b = blk >> 5, tile = blk & 31, l0 = tile * 64;
  int tid = threadIdx.x;
  int lane4 = tid & 15, rg = tid >> 4;      // rg 0..31: 8 rows each; lane4: 4 tokens each

  const float* vrow = v + ((size_t)b * D + rg * 8) * L + l0 + lane4 * 4;
  float4_ vv[8];
  float4_ s1 = {0.f, 0.f, 0.f, 0.f}, s2 = {0.f, 0.f, 0.f, 0.f};
  #pragma unroll
  for (int j = 0; j < 8; ++j) {
    float4_ x = *(const float4_*)&vrow[(size_t)j * L];
    vv[j] = x; s1 += x; s2 += x * x;
  }
  #pragma unroll
  for (int c = 0; c < 4; ++c) {
    part1[rg * 64 + lane4 * 4 + c] = s1[c];
    part2[rg * 64 + lane4 * 4 + c] = s2[c];
  }
  __syncthreads();
  if (tid < 64) {
    float a = 0.f, c = 0.f;
    #pragma unroll
    for (int q = 0; q < 32; ++q) { a += part1[q * 64 + tid]; c += part2[q * 64 + tid]; }
    float mu = a * (1.f / D);
    float var = c * (1.f / D) - mu * mu;
    float rsq = rsqrtf(var + EPS_LN);
    mu_s[tid] = mu; rs_s[tid] = rsq;
    m[b * L + l0 + tid] = mu;
    r[b * L + l0 + tid] = rsq;
  }
  __syncthreads();                           // part reads done -> ut may overwrite
  {
    #pragma unroll
    for (int c = 0; c < 4; ++c) {
      int tok = lane4 * 4 + c;
      float mu = mu_s[tok], rsv = rs_s[tok];
      #pragma unroll
      for (int j = 0; j < 8; ++j)
        ut[(rg * 8 + j) * 65 + tok] = (vv[j][c] - mu) * rsv;
    }
  }
  __syncthreads();
  {
    int d = tid >> 1, hf = (tid & 1) * 32;
    float a1 = 0.f, a2 = 0.f;
    #pragma unroll
    for (int l2 = 0; l2 < 32; ++l2) {
      float u = ut[d * 65 + hf + l2];
      a1 += u; a2 += u * u;
    }
    a1 += __shfl_xor(a1, 1, 64);
    a2 += __shfl_xor(a2, 1, 64);
    if ((tid & 1) == 0) {
      S1p[((size_t)b * 32 + tile) * D + d] = a1;
      S2p[((size_t)b * 32 + tile) * D + d] = a2;
    }
  }
}

// ---- per-b: reduce partials -> mu/sd over L -> q -> gw ----
__global__ void k_qproj(const float* __restrict__ S1p, const float* __restrict__ S2p,
                        const float* __restrict__ g, const float* __restrict__ be,
                        const float* __restrict__ wq, const float* __restrict__ wk,
                        float* __restrict__ gw) {
  __shared__ float cat[2 * D];
  __shared__ float qs[KP];
  int b = blockIdx.x, t = threadIdx.x;  // 256 threads
  {
    float s1 = 0.f, s2 = 0.f;
    for (int k = 0; k < 32; ++k) {
      s1 += S1p[((size_t)b * 32 + k) * D + t];
      s2 += S2p[((size_t)b * 32 + k) * D + t];
    }
    s1 *= (1.f / L); s2 *= (1.f / L);
    float gg = g[t];
    cat[t] = gg * s1 + be[t];
    float var = gg * gg * (s2 - s1 * s1);
    cat[D + t] = sqrtf(fmaxf(var, EPS_STAT));
  }
  __syncthreads();
  if (t < KP) {
    float s = 0.f;
    const float* wr = wq + t * 2 * D;
    for (int e = 0; e < 2 * D; ++e) s += cat[e] * wr[e];
    qs[t] = s;
  }
  __syncthreads();
  {
    float s = 0.f;
    for (int k = 0; k < KP; ++k) s += wk[k * D + t] * qs[k];
    gw[b * D + t] = g[t] * SCALE * s;  // beta const dropped (softmax-invariant)
  }
}

// ---- scores: float2 per lane -> 256 blocks (fill all CUs) ----
__global__ void k_scores(const float* __restrict__ v, const float* __restrict__ m,
                         const float* __restrict__ r, const float* __restrict__ gw,
                         float* __restrict__ sc) {
  __shared__ float gws[D];
  int i2 = blockIdx.x * 256 + threadIdx.x;
  int b = i2 >> 10, l = (i2 & 1023) * 2;    // 1024 float2 groups per b
  gws[threadIdx.x] = gw[b * D + threadIdx.x];
  __syncthreads();
  const float* p = v + (size_t)b * D * L + l;
  float2_ mm = *(const float2_*)&m[b * L + l];
  float2_ rr = *(const float2_*)&r[b * L + l];
  float2_ s = {0.f, 0.f};
  #pragma unroll 8
  for (int d = 0; d < D; ++d) {
    float2_ x = *(const float2_*)&p[(size_t)d * L];
    float g = gws[d];
    s += (x - mm) * g;
  }
  *(float2_*)&sc[b * L + l] = s * rr;
}

// ---- softmax (in-block recompute) + weighted stats over L per (b, 32 d-rows) ----
__global__ __launch_bounds__(256) void k_redw(
    const float* __restrict__ v, const float* __restrict__ m, const float* __restrict__ r,
    const float* __restrict__ sc, float* __restrict__ A1, float* __restrict__ A2) {
  __shared__ float ws[L];
  __shared__ float ms[L], rs[L];
  __shared__ float red[4];
  int blk = blockIdx.x;
  int b = blk >> 3, dt = (blk & 7) * 32;
  int tid = threadIdx.x, wv = tid >> 6, lane = tid & 63;

  float xc[8];
  float mx = -1e30f;
  #pragma unroll
  for (int k = 0; k < 8; ++k) {
    float x = sc[b * L + tid + k * 256];
    xc[k] = x; mx = fmaxf(mx, x);
  }
  mx = wredmax(mx);
  if (lane == 0) red[wv] = mx;
  __syncthreads();
  mx = fmaxf(fmaxf(red[0], red[1]), fmaxf(red[2], red[3]));
  float sm = 0.f;
  #pragma unroll
  for (int k = 0; k < 8; ++k) { float e = __expf(xc[k] - mx); xc[k] = e; sm += e; }
  sm = wred(sm);
  __syncthreads();
  if (lane == 0) red[wv] = sm;
  __syncthreads();
  float inv = 1.f / (red[0] + red[1] + red[2] + red[3]);
  #pragma unroll
  for (int k = 0; k < 8; ++k) ws[tid + k * 256] = xc[k] * inv;
  for (int l = tid; l < L; l += 256) { ms[l] = m[b * L + l]; rs[l] = r[b * L + l]; }
  __syncthreads();

  for (int j = 0; j < 8; ++j) {
    int d = dt + wv * 8 + j;
    const float* row = v + ((size_t)b * D + d) * L;
    float a1 = 0.f, a2 = 0.f;
    #pragma unroll
    for (int k2 = 0; k2 < 8; ++k2) {
      int l = lane * 4 + k2 * 256;
      float4_ x4 = *(const float4_*)&row[l];
      #pragma unroll
      for (int i = 0; i < 4; ++i) {
        float u = (x4[i] - ms[l + i]) * rs[l + i];
        float w = ws[l + i];
        a1 += w * u; a2 += w * u * u;
      }
    }
    a1 = wred(a1); a2 = wred(a2);
    if (lane == 0) { A1[b * D + d] = a1; A2[b * D + d] = a2; }
  }
}

// ---- per-b: att_mean/std -> skip (this layer) + fcq ----
__global__ void k_skip(const float* __restrict__ A1, const float* __restrict__ A2,
                       const float* __restrict__ g, const float* __restrict__ be,
                       const float* __restrict__ fcw, const float* __restrict__ fcb,
                       const float* __restrict__ fcqw,
                       float* __restrict__ skip_i, float* __restrict__ fcq) {
  __shared__ float am[D], as_[D];
  int b = blockIdx.x, t = threadIdx.x;
  {
    float a1 = A1[b * D + t], a2 = A2[b * D + t], gg = g[t];
    am[t] = gg * a1 + be[t];
    float var = gg * gg * (a2 - a1 * a1);
    as_[t] = sqrtf(fmaxf(var, EPS_STAT));
  }
  __syncthreads();
  float s = fcb[t], fq = 0.f;
  const float* wr = fcw + t * 2 * D;
  const float* qr = fcqw + t * D;
  for (int d = 0; d < D; ++d) {
    s += wr[d] * am[d] + wr[D + d] * as_[d];
    fq += qr[d] * am[d];
  }
  skip_i[b * D + t] = s;
  fcq[b * D + t] = fq;
}

// ---- fused FFN: 32x32x16 MFMA rework ----
// us layout unchanged: a_tile group g=d>>3 at us[(g*64+tok)*8+(d&7)];
// h1 group ((h>>3)+32)&63. 32x32 fragments read as single short8:
//   B-frag kk: us[((kk*2+hi)*64 + nt*32+lane31)*8], k = kk*16+hi*8+j.
// GEMM2 single pass (wave owns 32 d) -> LDS B-reads halved vs 16x16 split.
// C/D layout (m74): col=lane&31, row=(reg&3)+8*(reg>>2)+4*hi.
constexpr int MT = 64;

__global__ __launch_bounds__(512, 4) void k_ffn(
    const float* src, float* dst, const float* __restrict__ fcq,
    const unsigned short* __restrict__ w1b, const float* __restrict__ b1,
    const unsigned short* __restrict__ w2b, const float* __restrict__ b2,
    const float* __restrict__ g, const float* __restrict__ be) {
  __shared__ __align__(16) unsigned short us[32768];   // 64 KB
  __shared__ __align__(16) float fcq_s[D], g_s[D], be_s[D], b2_s[D];
  __shared__ __align__(16) float b1_s[H];
  __shared__ __align__(16) float mu_s[MT], rs_s[MT];
  float* part1 = (float*)us;            // [32][64] floats = 8KB (dead before pack)
  float* part2 = (float*)(us + 4096);   // next 8KB

  int blk = blockIdx.x;
  int b = blk >> 5;
  int l0 = (blk & 31) * MT;
  int tid = threadIdx.x;
  int lane4 = tid & 15, rg = tid >> 4;      // stage-1: rg 0..31 d-rows, 4 tokens each
  int wv = tid >> 6, lane = tid & 63;
  int lane31 = lane & 31, hi = lane >> 5;

  if (tid < D) {
    fcq_s[tid] = fcq[b * D + tid];
    g_s[tid] = g[tid]; be_s[tid] = be[tid]; b2_s[tid] = b2[tid];
  }
  b1_s[tid] = b1[tid];                       // 512 threads cover H
  __syncthreads();

  // ---- stage 1: vectorized load (8x float4), add fcq, token LN stats ----
  const float* vrow = src + ((size_t)b * D + rg * 8) * L + l0 + lane4 * 4;
  float4_ vv[8];
  float4_ s1 = {0.f, 0.f, 0.f, 0.f}, s2 = {0.f, 0.f, 0.f, 0.f};
  #pragma unroll
  for (int j = 0; j < 8; ++j) {
    float4_ x = *(const float4_*)&vrow[(size_t)j * L];
    x = x + fcq_s[rg * 8 + j];
    vv[j] = x; s1 += x; s2 += x * x;
  }
  *(float4_*)&part1[rg * 64 + lane4 * 4] = s1;
  *(float4_*)&part2[rg * 64 + lane4 * 4] = s2;
  __syncthreads();
  if (tid < MT) {
    float a = 0.f, c = 0.f;
    #pragma unroll
    for (int q = 0; q < 32; ++q) { a += part1[q * 64 + tid]; c += part2[q * 64 + tid]; }
    float mu = a * (1.f / D);
    float var = c * (1.f / D) - mu * mu;
    mu_s[tid] = mu; rs_s[tid] = rsqrtf(var + EPS_LN);
  }
  __syncthreads();                // part reads done; pack may overwrite
  {
    float4_ mu4 = *(const float4_*)&mu_s[lane4 * 4];
    float4_ rs4 = *(const float4_*)&rs_s[lane4 * 4];
    #pragma unroll
    for (int c = 0; c < 4; ++c) {
      uint4 pw;
      unsigned* pp = &pw.x;
      #pragma unroll
      for (int jj = 0; jj < 4; ++jj) {
        int d0 = rg * 8 + jj * 2;
        pp[jj] = pk2bf((vv[jj * 2][c]     - mu4[c]) * rs4[c] * g_s[d0]     + be_s[d0],
                       (vv[jj * 2 + 1][c] - mu4[c]) * rs4[c] * g_s[d0 + 1] + be_s[d0 + 1]);
      }
      *(uint4*)&us[(rg * 64 + lane4 * 4 + c) * 8] = pw;
    }
  }
  __syncthreads();

  // ---- GEMM1 (32x32x16): two halves of H; wave owns 32 h-rows per half ----
#define GEMM1_32(H0, ACC)                                                            \
  {                                                                                  \
    _Pragma("unroll")                                                                \
    for (int kk = 0; kk < 16; ++kk) {                                                \
      short8 a = *(const short8*)&w1b[(size_t)((H0) + lane31) * D + kk * 16 + hi * 8];\
      int base = (kk * 2 + hi) * 512;                                                \
      short8 b0 = *(const short8*)&us[base + lane31 * 8];                            \
      short8 b1f = *(const short8*)&us[base + (32 + lane31) * 8];                    \
      ACC[0] = __builtin_amdgcn_mfma_f32_32x32x16_bf16(a, b0, ACC[0], 0, 0, 0);      \
      ACC[1] = __builtin_amdgcn_mfma_f32_32x32x16_bf16(a, b1f, ACC[1], 0, 0, 0);     \
    }                                                                                \
  }

#define H1_WRITE_32(H0, ACC)                                                         \
  {                                                                                  \
    _Pragma("unroll")                                                                \
    for (int q = 0; q < 4; ++q) {                                                    \
      int hb = (H0) + hi * 4 + q * 8;                                                \
      float4_ bb = *(const float4_*)&b1_s[hb];                                       \
      int grp = (((H0) >> 3) + q + 32) & 63;                                         \
      _Pragma("unroll")                                                              \
      for (int nt = 0; nt < 2; ++nt) {                                               \
        int tok = nt * 32 + lane31;                                                  \
        uint2 pk;                                                                    \
        pk.x = pk2bf(fmaxf(ACC[nt][q * 4 + 0] + bb[0], 0.f),                         \
                     fmaxf(ACC[nt][q * 4 + 1] + bb[1], 0.f));                        \
        pk.y = pk2bf(fmaxf(ACC[nt][q * 4 + 2] + bb[2], 0.f),                         \
                     fmaxf(ACC[nt][q * 4 + 3] + bb[3], 0.f));                        \
        *(uint2*)&us[grp * 512 + tok * 8 + hi * 4] = pk;                             \
      }                                                                              \
    }                                                                                \
  }

  {
    f32x16 accA[2] = {};
    GEMM1_32(wv * 32, accA)
    H1_WRITE_32(wv * 32, accA)           // writes grps 32..63 (disjoint from a_tile)
  }
  {
    f32x16 accB[2] = {};
    GEMM1_32(256 + wv * 32, accB)
    __syncthreads();                     // all a_tile reads done (WAR)
    H1_WRITE_32(256 + wv * 32, accB)     // writes grps 0..31 (alias a_tile)
  }
  __syncthreads();                       // h1 fully visible

  // ---- GEMM2 (32x32x16): single pass, wave owns d = wv*32..+31 ----
  {
    f32x16 acc2[2] = {};
    int d0 = wv * 32;
    #pragma unroll
    for (int kk = 0; kk < 32; ++kk) {
      short8 a = *(const short8*)&w2b[(size_t)(d0 + lane31) * H + kk * 16 + hi * 8];
      int grp = ((kk * 2 + hi) + 32) & 63;
      short8 h0f = *(const short8*)&us[grp * 512 + lane31 * 8];
      short8 h1f = *(const short8*)&us[grp * 512 + (32 + lane31) * 8];
      acc2[0] = __builtin_amdgcn_mfma_f32_32x32x16_bf16(a, h0f, acc2[0], 0, 0, 0);
      acc2[1] = __builtin_amdgcn_mfma_f32_32x32x16_bf16(a, h1f, acc2[1], 0, 0, 0);
    }
    // epilogue: d = d0 + hi*4 + q*8 + rr, tok = nt*32 + lane31
    #pragma unroll
    for (int q = 0; q < 4; ++q) {
      int db = d0 + hi * 4 + q * 8;
      float4_ bb = *(const float4_*)&b2_s[db];
      float4_ fq = *(const float4_*)&fcq_s[db];
      #pragma unroll
      for (int rr = 0; rr < 4; ++rr) {
        int d = db + rr;
        float bias = bb[rr] + fq[rr];
        size_t rowoff = ((size_t)b * D + d) * L + l0;
        #pragma unroll
        for (int nt = 0; nt < 2; ++nt) {
          int tok = nt * 32 + lane31;
          dst[rowoff + tok] = acc2[nt][q * 4 + rr] + bias + src[rowoff + tok];
        }
      }
    }
  }
#undef GEMM1_32
#undef H1_WRITE_32
}

// ---- final: y = relu(skip0+skip1); batchnorm over B per channel d ----
__global__ void k_bn(const float* __restrict__ s0, const float* __restrict__ s1,
                     float* __restrict__ out) {
  int d = threadIdx.x;
  float s = 0.f, q = 0.f;
  for (int b = 0; b < B; ++b) {
    float y = fmaxf(s0[b * D + d] + s1[b * D + d], 0.f);
    s += y; q += y * y;
  }
  float mu = s * (1.f / B);
  float var = q * (1.f / B) - mu * mu;
  float rs = rsqrtf(var + EPS_BN);
  for (int b = 0; b < B; ++b) {
    float y = fmaxf(s0[b * D + d] + s1[b * D + d], 0.f);
    out[b * D + d] = (y - mu) * rs;
  }
}

extern "C" void kernel_launch(void* const* d_in, const int* in_sizes, int n_in,
                              void* d_out, int out_size, void* d_ws, size_t ws_size,
                              hipStream_t stream) {
  const float* x    = (const float*)d_in[0];
  const float* wk   = (const float*)d_in[1];
  const float* wq   = (const float*)d_in[2];
  const float* fcqw = (const float*)d_in[3];
  const float* fcw  = (const float*)d_in[4];
  const float* fcb  = (const float*)d_in[5];
  const float* ag   = (const float*)d_in[6];
  const float* abt  = (const float*)d_in[7];
  const float* w1   = (const float*)d_in[8];
  const float* b1   = (const float*)d_in[9];
  const float* w2   = (const float*)d_in[10];
  const float* b2   = (const float*)d_in[11];
  const float* fg   = (const float*)d_in[12];
  const float* fb   = (const float*)d_in[13];
  float* out = (float*)d_out;

  char* p = (char*)d_ws;
  float* v_ws = (float*)p;  p += (size_t)B * D * L * 4;
  float* m    = (float*)p;  p += (size_t)B * L * 4;
  float* r    = (float*)p;  p += (size_t)B * L * 4;
  float* sc   = (float*)p;  p += (size_t)B * L * 4;
  float* S1p  = (float*)p;  p += (size_t)B * 32 * D * 4;
  float* S2p  = (float*)p;  p += (size_t)B * 32 * D * 4;
  float* gw   = (float*)p;  p += (size_t)B * D * 4;
  float* A1   = (float*)p;  p += (size_t)B * D * 4;
  float* A2   = (float*)p;  p += (size_t)B * D * 4;
  float* fcqv = (float*)p;  p += (size_t)B * D * 4;
  float* sk0  = (float*)p;  p += (size_t)B * D * 4;
  float* sk1  = (float*)p;  p += (size_t)B * D * 4;
  unsigned short* w1b = (unsigned short*)p; p += (size_t)2 * H * D * 2;
  unsigned short* w2b = (unsigned short*)p; p += (size_t)2 * D * H * 2;

  k_convw<<<512, 256, 0, stream>>>(w1, w2, w1b, w2b);

  for (int i = 0; i < 2; ++i) {
    const float* src = (i == 0) ? x : v_ws;
    float* dst = v_ws;
    k_pass1<<<B * 32, 512, 0, stream>>>(src, m, r, S1p, S2p);
    k_qproj<<<B, 256, 0, stream>>>(S1p, S2p, ag + i * D, abt + i * D,
                                   wq + (size_t)i * KP * 2 * D,
                                   wk + (size_t)i * KP * D, gw);
    k_scores<<<B * L / 512, 256, 0, stream>>>(src, m, r, gw, sc);
    k_redw<<<B * 8, 256, 0, stream>>>(src, m, r, sc, A1, A2);
    k_skip<<<B, 256, 0, stream>>>(A1, A2, ag + i * D, abt + i * D,
                                  fcw + (size_t)i * D * 2 * D, fcb + i * D,
                                  fcqw + (size_t)i * D * D,
                                  (i == 0) ? sk0 : sk1, fcqv);
    k_ffn<<<B * (L / MT), 512, 0, stream>>>(src, dst, fcqv,
                                            w1b + (size_t)i * H * D, b1 + i * H,
                                            w2b + (size_t)i * D * H, b2 + i * D,
                                            fg + i * D, fb + i * D);
  }
  k_bn<<<1, 256, 0, stream>>>(sk0, sk1, out);
}

// Round 8
// 803.990 us; speedup vs baseline: 1.0011x; 1.0011x over previous
//
#include <hip/hip_runtime.h>
#include <hip/hip_bf16.h>

#define DEV __device__ __forceinline__

constexpr int B = 64, D = 256, L = 2048, H = 512, KP = 128;
constexpr float EPS_LN = 1e-6f, EPS_STAT = 1e-10f, EPS_BN = 1e-5f;
constexpr float SCALE = 0.088388347648318447f; // 1/sqrt(128)

typedef __attribute__((ext_vector_type(8))) short short8;
typedef __attribute__((ext_vector_type(4))) float float4_;
typedef __attribute__((ext_vector_type(2))) float float2_;
typedef __attribute__((ext_vector_type(16))) float f32x16;

DEV unsigned short f2bf(float x) {
  unsigned u = __builtin_bit_cast(unsigned, x);
  u += 0x7fffu + ((u >> 16) & 1u);           // RNE
  return (unsigned short)(u >> 16);
}

DEV unsigned pk2bf(float a, float b) {       // two RNE cvts packed into a dword
  return (unsigned)f2bf(a) | ((unsigned)f2bf(b) << 16);
}

DEV float wred(float x) {
  #pragma unroll
  for (int o = 32; o > 0; o >>= 1) x += __shfl_down(x, o, 64);
  return x;
}
DEV float wredmax(float x) {
  #pragma unroll
  for (int o = 32; o > 0; o >>= 1) x = fmaxf(x, __shfl_down(x, o, 64));
  return x;
}

// ---- convert w1/w2 (both layers) to bf16 ----
__global__ void k_convw(const float* __restrict__ w1, const float* __restrict__ w2,
                        unsigned short* __restrict__ w1b, unsigned short* __restrict__ w2b) {
  int n = 2 * H * D;
  for (int i = blockIdx.x * blockDim.x + threadIdx.x; i < n; i += gridDim.x * blockDim.x) {
    w1b[i] = f2bf(w1[i]);
    w2b[i] = f2bf(w2[i]);
  }
}

// ---- P1: fused token-LN stats (m,r) + per-(b,d,tile) partial sums of u,u^2 ----
__global__ __launch_bounds__(512, 4) void k_pass1(
    const float* __restrict__ v, float* __restrict__ m, float* __restrict__ r,
    float* __restrict__ S1p, float* __restrict__ S2p) {
  __shared__ float ut[256 * 65];            // u (fp32), row d stride 65 (pad); front 16KB = parts
  __shared__ float mu_s[64], rs_s[64];
  float* part1 = ut;                        // [32][64] floats = 8KB (dead before ut written)
  float* part2 = ut + 2048;                 // [32][64]

  int blk = blockIdx.x;
  int b = blk >> 5, tile = blk & 31, l0 = tile * 64;
  int tid = threadIdx.x;
  int lane4 = tid & 15, rg = tid >> 4;      // rg 0..31: 8 rows each; lane4: 4 tokens each

  const float* vrow = v + ((size_t)b * D + rg * 8) * L + l0 + lane4 * 4;
  float4_ vv[8];
  float4_ s1 = {0.f, 0.f, 0.f, 0.f}, s2 = {0.f, 0.f, 0.f, 0.f};
  #pragma unroll
  for (int j = 0; j < 8; ++j) {
    float4_ x = *(const float4_*)&vrow[(size_t)j * L];
    vv[j] = x; s1 += x; s2 += x * x;
  }
  #pragma unroll
  for (int c = 0; c < 4; ++c) {
    part1[rg * 64 + lane4 * 4 + c] = s1[c];
    part2[rg * 64 + lane4 * 4 + c] = s2[c];
  }
  __syncthreads();
  if (tid < 64) {
    float a = 0.f, c = 0.f;
    #pragma unroll
    for (int q = 0; q < 32; ++q) { a += part1[q * 64 + tid]; c += part2[q * 64 + tid]; }
    float mu = a * (1.f / D);
    float var = c * (1.f / D) - mu * mu;
    float rsq = rsqrtf(var + EPS_LN);
    mu_s[tid] = mu; rs_s[tid] = rsq;
    m[b * L + l0 + tid] = mu;
    r[b * L + l0 + tid] = rsq;
  }
  __syncthreads();                           // part reads done -> ut may overwrite
  {
    #pragma unroll
    for (int c = 0; c < 4; ++c) {
      int tok = lane4 * 4 + c;
      float mu = mu_s[tok], rsv = rs_s[tok];
      #pragma unroll
      for (int j = 0; j < 8; ++j)
        ut[(rg * 8 + j) * 65 + tok] = (vv[j][c] - mu) * rsv;
    }
  }
  __syncthreads();
  {
    int d = tid >> 1, hf = (tid & 1) * 32;
    float a1 = 0.f, a2 = 0.f;
    #pragma unroll
    for (int l2 = 0; l2 < 32; ++l2) {
      float u = ut[d * 65 + hf + l2];
      a1 += u; a2 += u * u;
    }
    a1 += __shfl_xor(a1, 1, 64);
    a2 += __shfl_xor(a2, 1, 64);
    if ((tid & 1) == 0) {
      S1p[((size_t)b * 32 + tile) * D + d] = a1;
      S2p[((size_t)b * 32 + tile) * D + d] = a2;
    }
  }
}

// ---- per-b: reduce partials -> mu/sd over L -> q -> gw ----
__global__ void k_qproj(const float* __restrict__ S1p, const float* __restrict__ S2p,
                        const float* __restrict__ g, const float* __restrict__ be,
                        const float* __restrict__ wq, const float* __restrict__ wk,
                        float* __restrict__ gw) {
  __shared__ float cat[2 * D];
  __shared__ float qs[KP];
  int b = blockIdx.x, t = threadIdx.x;  // 256 threads
  {
    float s1 = 0.f, s2 = 0.f;
    for (int k = 0; k < 32; ++k) {
      s1 += S1p[((size_t)b * 32 + k) * D + t];
      s2 += S2p[((size_t)b * 32 + k) * D + t];
    }
    s1 *= (1.f / L); s2 *= (1.f / L);
    float gg = g[t];
    cat[t] = gg * s1 + be[t];
    float var = gg * gg * (s2 - s1 * s1);
    cat[D + t] = sqrtf(fmaxf(var, EPS_STAT));
  }
  __syncthreads();
  if (t < KP) {
    float s = 0.f;
    const float* wr = wq + t * 2 * D;
    for (int e = 0; e < 2 * D; ++e) s += cat[e] * wr[e];
    qs[t] = s;
  }
  __syncthreads();
  {
    float s = 0.f;
    for (int k = 0; k < KP; ++k) s += wk[k * D + t] * qs[k];
    gw[b * D + t] = g[t] * SCALE * s;  // beta const dropped (softmax-invariant)
  }
}

// ---- scores: float2 per lane -> 256 blocks (fill all CUs) ----
__global__ void k_scores(const float* __restrict__ v, const float* __restrict__ m,
                         const float* __restrict__ r, const float* __restrict__ gw,
                         float* __restrict__ sc) {
  __shared__ float gws[D];
  int i2 = blockIdx.x * 256 + threadIdx.x;
  int b = i2 >> 10, l = (i2 & 1023) * 2;    // 1024 float2 groups per b
  gws[threadIdx.x] = gw[b * D + threadIdx.x];
  __syncthreads();
  const float* p = v + (size_t)b * D * L + l;
  float2_ mm = *(const float2_*)&m[b * L + l];
  float2_ rr = *(const float2_*)&r[b * L + l];
  float2_ s = {0.f, 0.f};
  #pragma unroll 8
  for (int d = 0; d < D; ++d) {
    float2_ x = *(const float2_*)&p[(size_t)d * L];
    float g = gws[d];
    s += (x - mm) * g;
  }
  *(float2_*)&sc[b * L + l] = s * rr;
}

// ---- softmax (in-block recompute) + weighted stats over L per (b, 32 d-rows) ----
__global__ __launch_bounds__(256) void k_redw(
    const float* __restrict__ v, const float* __restrict__ m, const float* __restrict__ r,
    const float* __restrict__ sc, float* __restrict__ A1, float* __restrict__ A2) {
  __shared__ float ws[L];
  __shared__ float ms[L], rs[L];
  __shared__ float red[4];
  int blk = blockIdx.x;
  int b = blk >> 3, dt = (blk & 7) * 32;
  int tid = threadIdx.x, wv = tid >> 6, lane = tid & 63;

  float xc[8];
  float mx = -1e30f;
  #pragma unroll
  for (int k = 0; k < 8; ++k) {
    float x = sc[b * L + tid + k * 256];
    xc[k] = x; mx = fmaxf(mx, x);
  }
  mx = wredmax(mx);
  if (lane == 0) red[wv] = mx;
  __syncthreads();
  mx = fmaxf(fmaxf(red[0], red[1]), fmaxf(red[2], red[3]));
  float sm = 0.f;
  #pragma unroll
  for (int k = 0; k < 8; ++k) { float e = __expf(xc[k] - mx); xc[k] = e; sm += e; }
  sm = wred(sm);
  __syncthreads();
  if (lane == 0) red[wv] = sm;
  __syncthreads();
  float inv = 1.f / (red[0] + red[1] + red[2] + red[3]);
  #pragma unroll
  for (int k = 0; k < 8; ++k) ws[tid + k * 256] = xc[k] * inv;
  for (int l = tid; l < L; l += 256) { ms[l] = m[b * L + l]; rs[l] = r[b * L + l]; }
  __syncthreads();

  for (int j = 0; j < 8; ++j) {
    int d = dt + wv * 8 + j;
    const float* row = v + ((size_t)b * D + d) * L;
    float a1 = 0.f, a2 = 0.f;
    #pragma unroll
    for (int k2 = 0; k2 < 8; ++k2) {
      int l = lane * 4 + k2 * 256;
      float4_ x4 = *(const float4_*)&row[l];
      #pragma unroll
      for (int i = 0; i < 4; ++i) {
        float u = (x4[i] - ms[l + i]) * rs[l + i];
        float w = ws[l + i];
        a1 += w * u; a2 += w * u * u;
      }
    }
    a1 = wred(a1); a2 = wred(a2);
    if (lane == 0) { A1[b * D + d] = a1; A2[b * D + d] = a2; }
  }
}

// ---- per-b: att_mean/std -> skip (this layer) + fcq ----
__global__ void k_skip(const float* __restrict__ A1, const float* __restrict__ A2,
                       const float* __restrict__ g, const float* __restrict__ be,
                       const float* __restrict__ fcw, const float* __restrict__ fcb,
                       const float* __restrict__ fcqw,
                       float* __restrict__ skip_i, float* __restrict__ fcq) {
  __shared__ float am[D], as_[D];
  int b = blockIdx.x, t = threadIdx.x;
  {
    float a1 = A1[b * D + t], a2 = A2[b * D + t], gg = g[t];
    am[t] = gg * a1 + be[t];
    float var = gg * gg * (a2 - a1 * a1);
    as_[t] = sqrtf(fmaxf(var, EPS_STAT));
  }
  __syncthreads();
  float s = fcb[t], fq = 0.f;
  const float* wr = fcw + t * 2 * D;
  const float* qr = fcqw + t * D;
  for (int d = 0; d < D; ++d) {
    s += wr[d] * am[d] + wr[D + d] * as_[d];
    fq += qr[d] * am[d];
  }
  skip_i[b * D + t] = s;
  fcq[b * D + t] = fq;
}

// ---- fused FFN: 32x32x16 MFMA + 8-deep chunked A-prefetch (round-1 pattern) ----
// us layout: a_tile group g=d>>3 at us[(g*64+tok)*8+(d&7)]; h1 group ((h>>3)+32)&63.
// B-frag kk: us[((kk*2+hi)*64 + nt*32+lane31)*8], k = kk*16+hi*8+j.
// C/D layout (m74): col=lane&31, row=(reg&3)+8*(reg>>2)+4*hi.
// Weight A-frags prefetched 8-deep (32 VGPR) per chunk -> one L2 latency/chunk.
constexpr int MT = 64;

__global__ __launch_bounds__(512, 4) void k_ffn(
    const float* src, float* dst, const float* __restrict__ fcq,
    const unsigned short* __restrict__ w1b, const float* __restrict__ b1,
    const unsigned short* __restrict__ w2b, const float* __restrict__ b2,
    const float* __restrict__ g, const float* __restrict__ be) {
  __shared__ __align__(16) unsigned short us[32768];   // 64 KB
  __shared__ __align__(16) float fcq_s[D], g_s[D], be_s[D], b2_s[D];
  __shared__ __align__(16) float b1_s[H];
  __shared__ __align__(16) float mu_s[MT], rs_s[MT];
  float* part1 = (float*)us;            // [32][64] floats = 8KB (dead before pack)
  float* part2 = (float*)(us + 4096);   // next 8KB

  int blk = blockIdx.x;
  int b = blk >> 5;
  int l0 = (blk & 31) * MT;
  int tid = threadIdx.x;
  int lane4 = tid & 15, rg = tid >> 4;      // stage-1: rg 0..31 d-rows, 4 tokens each
  int wv = tid >> 6, lane = tid & 63;
  int lane31 = lane & 31, hi = lane >> 5;

  if (tid < D) {
    fcq_s[tid] = fcq[b * D + tid];
    g_s[tid] = g[tid]; be_s[tid] = be[tid]; b2_s[tid] = b2[tid];
  }
  b1_s[tid] = b1[tid];                       // 512 threads cover H
  __syncthreads();

  // ---- stage 1: vectorized load (8x float4), add fcq, token LN stats ----
  const float* vrow = src + ((size_t)b * D + rg * 8) * L + l0 + lane4 * 4;
  float4_ vv[8];
  float4_ s1 = {0.f, 0.f, 0.f, 0.f}, s2 = {0.f, 0.f, 0.f, 0.f};
  #pragma unroll
  for (int j = 0; j < 8; ++j) {
    float4_ x = *(const float4_*)&vrow[(size_t)j * L];
    x = x + fcq_s[rg * 8 + j];
    vv[j] = x; s1 += x; s2 += x * x;
  }
  *(float4_*)&part1[rg * 64 + lane4 * 4] = s1;
  *(float4_*)&part2[rg * 64 + lane4 * 4] = s2;
  __syncthreads();
  if (tid < MT) {
    float a = 0.f, c = 0.f;
    #pragma unroll
    for (int q = 0; q < 32; ++q) { a += part1[q * 64 + tid]; c += part2[q * 64 + tid]; }
    float mu = a * (1.f / D);
    float var = c * (1.f / D) - mu * mu;
    mu_s[tid] = mu; rs_s[tid] = rsqrtf(var + EPS_LN);
  }
  __syncthreads();                // part reads done; pack may overwrite
  {
    float4_ mu4 = *(const float4_*)&mu_s[lane4 * 4];
    float4_ rs4 = *(const float4_*)&rs_s[lane4 * 4];
    #pragma unroll
    for (int c = 0; c < 4; ++c) {
      uint4 pw;
      unsigned* pp = &pw.x;
      #pragma unroll
      for (int jj = 0; jj < 4; ++jj) {
        int d0 = rg * 8 + jj * 2;
        pp[jj] = pk2bf((vv[jj * 2][c]     - mu4[c]) * rs4[c] * g_s[d0]     + be_s[d0],
                       (vv[jj * 2 + 1][c] - mu4[c]) * rs4[c] * g_s[d0 + 1] + be_s[d0 + 1]);
      }
      *(uint4*)&us[(rg * 64 + lane4 * 4 + c) * 8] = pw;
    }
  }
  __syncthreads();

  // ---- GEMM1 (32x32x16): 8-deep A-prefetch, 2 chunks per half ----
#define GEMM1_32(H0, ACC)                                                            \
  {                                                                                  \
    const unsigned short* wp = w1b + (size_t)((H0) + lane31) * D + hi * 8;           \
    _Pragma("unroll")                                                                \
    for (int c = 0; c < 2; ++c) {                                                    \
      short8 aw[8];                                                                  \
      _Pragma("unroll")                                                              \
      for (int k2 = 0; k2 < 8; ++k2)                                                 \
        aw[k2] = *(const short8*)(wp + (c * 8 + k2) * 16);                           \
      _Pragma("unroll")                                                              \
      for (int k2 = 0; k2 < 8; ++k2) {                                               \
        int kk = c * 8 + k2;                                                         \
        int base = (kk * 2 + hi) * 512;                                              \
        short8 b0 = *(const short8*)&us[base + lane31 * 8];                          \
        short8 b1f = *(const short8*)&us[base + (32 + lane31) * 8];                  \
        ACC[0] = __builtin_amdgcn_mfma_f32_32x32x16_bf16(aw[k2], b0, ACC[0], 0, 0, 0);\
        ACC[1] = __builtin_amdgcn_mfma_f32_32x32x16_bf16(aw[k2], b1f, ACC[1], 0, 0, 0);\
      }                                                                              \
    }                                                                                \
  }

#define H1_WRITE_32(H0, ACC)                                                         \
  {                                                                                  \
    _Pragma("unroll")                                                                \
    for (int q = 0; q < 4; ++q) {                                                    \
      int hb = (H0) + hi * 4 + q * 8;                                                \
      float4_ bb = *(const float4_*)&b1_s[hb];                                       \
      int grp = (((H0) >> 3) + q + 32) & 63;                                         \
      _Pragma("unroll")                                                              \
      for (int nt = 0; nt < 2; ++nt) {                                               \
        int tok = nt * 32 + lane31;                                                  \
        uint2 pk;                                                                    \
        pk.x = pk2bf(fmaxf(ACC[nt][q * 4 + 0] + bb[0], 0.f),                         \
                     fmaxf(ACC[nt][q * 4 + 1] + bb[1], 0.f));                        \
        pk.y = pk2bf(fmaxf(ACC[nt][q * 4 + 2] + bb[2], 0.f),                         \
                     fmaxf(ACC[nt][q * 4 + 3] + bb[3], 0.f));                        \
        *(uint2*)&us[grp * 512 + tok * 8 + hi * 4] = pk;                             \
      }                                                                              \
    }                                                                                \
  }

  {
    f32x16 accA[2] = {};
    GEMM1_32(wv * 32, accA)
    H1_WRITE_32(wv * 32, accA)           // writes grps 32..63 (disjoint from a_tile)
  }
  {
    f32x16 accB[2] = {};
    GEMM1_32(256 + wv * 32, accB)
    __syncthreads();                     // all a_tile reads done (WAR)
    H1_WRITE_32(256 + wv * 32, accB)     // writes grps 0..31 (alias a_tile)
  }
  __syncthreads();                       // h1 fully visible

  // ---- GEMM2 (32x32x16): single pass, wave owns d = wv*32..+31; 4 chunks of 8 ----
  {
    f32x16 acc2[2] = {};
    int d0 = wv * 32;
    const unsigned short* wp = w2b + (size_t)(d0 + lane31) * H + hi * 8;
    #pragma unroll
    for (int c = 0; c < 4; ++c) {
      short8 aw[8];
      #pragma unroll
      for (int k2 = 0; k2 < 8; ++k2)
        aw[k2] = *(const short8*)(wp + (c * 8 + k2) * 16);
      #pragma unroll
      for (int k2 = 0; k2 < 8; ++k2) {
        int kk = c * 8 + k2;
        int grp = ((kk * 2 + hi) + 32) & 63;
        short8 h0f = *(const short8*)&us[grp * 512 + lane31 * 8];
        short8 h1f = *(const short8*)&us[grp * 512 + (32 + lane31) * 8];
        acc2[0] = __builtin_amdgcn_mfma_f32_32x32x16_bf16(aw[k2], h0f, acc2[0], 0, 0, 0);
        acc2[1] = __builtin_amdgcn_mfma_f32_32x32x16_bf16(aw[k2], h1f, acc2[1], 0, 0, 0);
      }
    }
    // epilogue: d = d0 + hi*4 + q*8 + rr, tok = nt*32 + lane31
    #pragma unroll
    for (int q = 0; q < 4; ++q) {
      int db = d0 + hi * 4 + q * 8;
      float4_ bb = *(const float4_*)&b2_s[db];
      float4_ fq = *(const float4_*)&fcq_s[db];
      #pragma unroll
      for (int rr = 0; rr < 4; ++rr) {
        int d = db + rr;
        float bias = bb[rr] + fq[rr];
        size_t rowoff = ((size_t)b * D + d) * L + l0;
        #pragma unroll
        for (int nt = 0; nt < 2; ++nt) {
          int tok = nt * 32 + lane31;
          dst[rowoff + tok] = acc2[nt][q * 4 + rr] + bias + src[rowoff + tok];
        }
      }
    }
  }
#undef GEMM1_32
#undef H1_WRITE_32
}

// ---- final: y = relu(skip0+skip1); batchnorm over B per channel d ----
__global__ void k_bn(const float* __restrict__ s0, const float* __restrict__ s1,
                     float* __restrict__ out) {
  int d = threadIdx.x;
  float s = 0.f, q = 0.f;
  for (int b = 0; b < B; ++b) {
    float y = fmaxf(s0[b * D + d] + s1[b * D + d], 0.f);
    s += y; q += y * y;
  }
  float mu = s * (1.f / B);
  float var = q * (1.f / B) - mu * mu;
  float rs = rsqrtf(var + EPS_BN);
  for (int b = 0; b < B; ++b) {
    float y = fmaxf(s0[b * D + d] + s1[b * D + d], 0.f);
    out[b * D + d] = (y - mu) * rs;
  }
}

extern "C" void kernel_launch(void* const* d_in, const int* in_sizes, int n_in,
                              void* d_out, int out_size, void* d_ws, size_t ws_size,
                              hipStream_t stream) {
  const float* x    = (const float*)d_in[0];
  const float* wk   = (const float*)d_in[1];
  const float* wq   = (const float*)d_in[2];
  const float* fcqw = (const float*)d_in[3];
  const float* fcw  = (const float*)d_in[4];
  const float* fcb  = (const float*)d_in[5];
  const float* ag   = (const float*)d_in[6];
  const float* abt  = (const float*)d_in[7];
  const float* w1   = (const float*)d_in[8];
  const float* b1   = (const float*)d_in[9];
  const float* w2   = (const float*)d_in[10];
  const float* b2   = (const float*)d_in[11];
  const float* fg   = (const float*)d_in[12];
  const float* fb   = (const float*)d_in[13];
  float* out = (float*)d_out;

  char* p = (char*)d_ws;
  float* v_ws = (float*)p;  p += (size_t)B * D * L * 4;
  float* m    = (float*)p;  p += (size_t)B * L * 4;
  float* r    = (float*)p;  p += (size_t)B * L * 4;
  float* sc   = (float*)p;  p += (size_t)B * L * 4;
  float* S1p  = (float*)p;  p += (size_t)B * 32 * D * 4;
  float* S2p  = (float*)p;  p += (size_t)B * 32 * D * 4;
  float* gw   = (float*)p;  p += (size_t)B * D * 4;
  float* A1   = (float*)p;  p += (size_t)B * D * 4;
  float* A2   = (float*)p;  p += (size_t)B * D * 4;
  float* fcqv = (float*)p;  p += (size_t)B * D * 4;
  float* sk0  = (float*)p;  p += (size_t)B * D * 4;
  float* sk1  = (float*)p;  p += (size_t)B * D * 4;
  unsigned short* w1b = (unsigned short*)p; p += (size_t)2 * H * D * 2;
  unsigned short* w2b = (unsigned short*)p; p += (size_t)2 * D * H * 2;

  k_convw<<<512, 256, 0, stream>>>(w1, w2, w1b, w2b);

  for (int i = 0; i < 2; ++i) {
    const float* src = (i == 0) ? x : v_ws;
    float* dst = v_ws;
    k_pass1<<<B * 32, 512, 0, stream>>>(src, m, r, S1p, S2p);
    k_qproj<<<B, 256, 0, stream>>>(S1p, S2p, ag + i * D, abt + i * D,
                                   wq + (size_t)i * KP * 2 * D,
                                   wk + (size_t)i * KP * D, gw);
    k_scores<<<B * L / 512, 256, 0, stream>>>(src, m, r, gw, sc);
    k_redw<<<B * 8, 256, 0, stream>>>(src, m, r, sc, A1, A2);
    k_skip<<<B, 256, 0, stream>>>(A1, A2, ag + i * D, abt + i * D,
                                  fcw + (size_t)i * D * 2 * D, fcb + i * D,
                                  fcqw + (size_t)i * D * D,
                                  (i == 0) ? sk0 : sk1, fcqv);
    k_ffn<<<B * (L / MT), 512, 0, stream>>>(src, dst, fcqv,
                                            w1b + (size_t)i * H * D, b1 + i * H,
                                            w2b + (size_t)i * D * H, b2 + i * D,
                                            fg + i * D, fb + i * D);
  }
  k_bn<<<1, 256, 0, stream>>>(sk0, sk1, out);
}

// Round 9
// 619.423 us; speedup vs baseline: 1.2994x; 1.2980x over previous
//
#include <hip/hip_runtime.h>
#include <hip/hip_bf16.h>

#define DEV __device__ __forceinline__

constexpr int B = 64, D = 256, L = 2048, H = 512, KP = 128;
constexpr float EPS_LN = 1e-6f, EPS_STAT = 1e-10f, EPS_BN = 1e-5f;
constexpr float SCALE = 0.088388347648318447f; // 1/sqrt(128)

typedef __attribute__((ext_vector_type(8))) short short8;
typedef __attribute__((ext_vector_type(4))) float float4_;
typedef __attribute__((ext_vector_type(2))) float float2_;

DEV unsigned short f2bf(float x) {
  unsigned u = __builtin_bit_cast(unsigned, x);
  u += 0x7fffu + ((u >> 16) & 1u);           // RNE
  return (unsigned short)(u >> 16);
}

DEV unsigned pk2bf(float a, float b) {       // two RNE cvts packed into a dword
  return (unsigned)f2bf(a) | ((unsigned)f2bf(b) << 16);
}

DEV float wred(float x) {
  #pragma unroll
  for (int o = 32; o > 0; o >>= 1) x += __shfl_down(x, o, 64);
  return x;
}
DEV float wredmax(float x) {
  #pragma unroll
  for (int o = 32; o > 0; o >>= 1) x = fmaxf(x, __shfl_down(x, o, 64));
  return x;
}

// ---- convert w1/w2 (layer 0 only; layer-1 FFN is dead code) ----
__global__ void k_convw(const float* __restrict__ w1, const float* __restrict__ w2,
                        unsigned short* __restrict__ w1b, unsigned short* __restrict__ w2b) {
  int n = H * D;
  for (int i = blockIdx.x * blockDim.x + threadIdx.x; i < n; i += gridDim.x * blockDim.x) {
    w1b[i] = f2bf(w1[i]);
    w2b[i] = f2bf(w2[i]);
  }
}

// ---- P1: fused token-LN stats (m,r) + per-(b,d,tile) partial sums of u,u^2 ----
// float4 loads (16 lanes x 4 tokens, 8 rows/thread); LN partials alias front of ut.
__global__ __launch_bounds__(512, 4) void k_pass1(
    const float* __restrict__ v, float* __restrict__ m, float* __restrict__ r,
    float* __restrict__ S1p, float* __restrict__ S2p) {
  __shared__ float ut[256 * 65];            // u (fp32), row d stride 65 (pad); front 16KB = parts
  __shared__ float mu_s[64], rs_s[64];
  float* part1 = ut;                        // [32][64] floats = 8KB (dead before ut written)
  float* part2 = ut + 2048;                 // [32][64]

  int blk = blockIdx.x;
  int b = blk >> 5, tile = blk & 31, l0 = tile * 64;
  int tid = threadIdx.x;
  int lane4 = tid & 15, rg = tid >> 4;      // rg 0..31: 8 rows each; lane4: 4 tokens each

  const float* vrow = v + ((size_t)b * D + rg * 8) * L + l0 + lane4 * 4;
  float4_ vv[8];
  float4_ s1 = {0.f, 0.f, 0.f, 0.f}, s2 = {0.f, 0.f, 0.f, 0.f};
  #pragma unroll
  for (int j = 0; j < 8; ++j) {
    float4_ x = *(const float4_*)&vrow[(size_t)j * L];
    vv[j] = x; s1 += x; s2 += x * x;
  }
  #pragma unroll
  for (int c = 0; c < 4; ++c) {
    part1[rg * 64 + lane4 * 4 + c] = s1[c];
    part2[rg * 64 + lane4 * 4 + c] = s2[c];
  }
  __syncthreads();
  if (tid < 64) {
    float a = 0.f, c = 0.f;
    #pragma unroll
    for (int q = 0; q < 32; ++q) { a += part1[q * 64 + tid]; c += part2[q * 64 + tid]; }
    float mu = a * (1.f / D);
    float var = c * (1.f / D) - mu * mu;
    float rsq = rsqrtf(var + EPS_LN);
    mu_s[tid] = mu; rs_s[tid] = rsq;
    m[b * L + l0 + tid] = mu;
    r[b * L + l0 + tid] = rsq;
  }
  __syncthreads();                           // part reads done -> ut may overwrite
  {
    #pragma unroll
    for (int c = 0; c < 4; ++c) {
      int tok = lane4 * 4 + c;
      float mu = mu_s[tok], rsv = rs_s[tok];
      #pragma unroll
      for (int j = 0; j < 8; ++j)
        ut[(rg * 8 + j) * 65 + tok] = (vv[j][c] - mu) * rsv;
    }
  }
  __syncthreads();
  {
    int d = tid >> 1, hf = (tid & 1) * 32;
    float a1 = 0.f, a2 = 0.f;
    #pragma unroll
    for (int l2 = 0; l2 < 32; ++l2) {
      float u = ut[d * 65 + hf + l2];
      a1 += u; a2 += u * u;
    }
    a1 += __shfl_xor(a1, 1, 64);
    a2 += __shfl_xor(a2, 1, 64);
    if ((tid & 1) == 0) {
      S1p[((size_t)b * 32 + tile) * D + d] = a1;
      S2p[((size_t)b * 32 + tile) * D + d] = a2;
    }
  }
}

// ---- per-b: reduce partials -> mu/sd over L -> q -> gw ----
__global__ void k_qproj(const float* __restrict__ S1p, const float* __restrict__ S2p,
                        const float* __restrict__ g, const float* __restrict__ be,
                        const float* __restrict__ wq, const float* __restrict__ wk,
                        float* __restrict__ gw) {
  __shared__ float cat[2 * D];
  __shared__ float qs[KP];
  int b = blockIdx.x, t = threadIdx.x;  // 256 threads
  {
    float s1 = 0.f, s2 = 0.f;
    for (int k = 0; k < 32; ++k) {
      s1 += S1p[((size_t)b * 32 + k) * D + t];
      s2 += S2p[((size_t)b * 32 + k) * D + t];
    }
    s1 *= (1.f / L); s2 *= (1.f / L);
    float gg = g[t];
    cat[t] = gg * s1 + be[t];
    float var = gg * gg * (s2 - s1 * s1);
    cat[D + t] = sqrtf(fmaxf(var, EPS_STAT));
  }
  __syncthreads();
  if (t < KP) {
    float s = 0.f;
    const float* wr = wq + t * 2 * D;
    for (int e = 0; e < 2 * D; ++e) s += cat[e] * wr[e];
    qs[t] = s;
  }
  __syncthreads();
  {
    float s = 0.f;
    for (int k = 0; k < KP; ++k) s += wk[k * D + t] * qs[k];
    gw[b * D + t] = g[t] * SCALE * s;  // beta const dropped (softmax-invariant)
  }
}

// ---- scores: float2 per lane -> 256 blocks (fill all CUs) ----
__global__ void k_scores(const float* __restrict__ v, const float* __restrict__ m,
                         const float* __restrict__ r, const float* __restrict__ gw,
                         float* __restrict__ sc) {
  __shared__ float gws[D];
  int i2 = blockIdx.x * 256 + threadIdx.x;
  int b = i2 >> 10, l = (i2 & 1023) * 2;    // 1024 float2 groups per b
  gws[threadIdx.x] = gw[b * D + threadIdx.x];
  __syncthreads();
  const float* p = v + (size_t)b * D * L + l;
  float2_ mm = *(const float2_*)&m[b * L + l];
  float2_ rr = *(const float2_*)&r[b * L + l];
  float2_ s = {0.f, 0.f};
  #pragma unroll 8
  for (int d = 0; d < D; ++d) {
    float2_ x = *(const float2_*)&p[(size_t)d * L];
    float g = gws[d];
    s += (x - mm) * g;
  }
  *(float2_*)&sc[b * L + l] = s * rr;
}

// ---- softmax (in-block recompute) + weighted stats over L per (b, 32 d-rows) ----
__global__ __launch_bounds__(256) void k_redw(
    const float* __restrict__ v, const float* __restrict__ m, const float* __restrict__ r,
    const float* __restrict__ sc, float* __restrict__ A1, float* __restrict__ A2) {
  __shared__ float ws[L];
  __shared__ float ms[L], rs[L];
  __shared__ float red[4];
  int blk = blockIdx.x;
  int b = blk >> 3, dt = (blk & 7) * 32;
  int tid = threadIdx.x, wv = tid >> 6, lane = tid & 63;

  float xc[8];
  float mx = -1e30f;
  #pragma unroll
  for (int k = 0; k < 8; ++k) {
    float x = sc[b * L + tid + k * 256];
    xc[k] = x; mx = fmaxf(mx, x);
  }
  mx = wredmax(mx);
  if (lane == 0) red[wv] = mx;
  __syncthreads();
  mx = fmaxf(fmaxf(red[0], red[1]), fmaxf(red[2], red[3]));
  float sm = 0.f;
  #pragma unroll
  for (int k = 0; k < 8; ++k) { float e = __expf(xc[k] - mx); xc[k] = e; sm += e; }
  sm = wred(sm);
  __syncthreads();
  if (lane == 0) red[wv] = sm;
  __syncthreads();
  float inv = 1.f / (red[0] + red[1] + red[2] + red[3]);
  #pragma unroll
  for (int k = 0; k < 8; ++k) ws[tid + k * 256] = xc[k] * inv;
  for (int l = tid; l < L; l += 256) { ms[l] = m[b * L + l]; rs[l] = r[b * L + l]; }
  __syncthreads();

  for (int j = 0; j < 8; ++j) {
    int d = dt + wv * 8 + j;
    const float* row = v + ((size_t)b * D + d) * L;
    float a1 = 0.f, a2 = 0.f;
    #pragma unroll
    for (int k2 = 0; k2 < 8; ++k2) {
      int l = lane * 4 + k2 * 256;
      float4_ x4 = *(const float4_*)&row[l];
      #pragma unroll
      for (int i = 0; i < 4; ++i) {
        float u = (x4[i] - ms[l + i]) * rs[l + i];
        float w = ws[l + i];
        a1 += w * u; a2 += w * u * u;
      }
    }
    a1 = wred(a1); a2 = wred(a2);
    if (lane == 0) { A1[b * D + d] = a1; A2[b * D + d] = a2; }
  }
}

// ---- per-b: att_mean/std -> skip (this layer) + fcq ----
__global__ void k_skip(const float* __restrict__ A1, const float* __restrict__ A2,
                       const float* __restrict__ g, const float* __restrict__ be,
                       const float* __restrict__ fcw, const float* __restrict__ fcb,
                       const float* __restrict__ fcqw,
                       float* __restrict__ skip_i, float* __restrict__ fcq) {
  __shared__ float am[D], as_[D];
  int b = blockIdx.x, t = threadIdx.x;
  {
    float a1 = A1[b * D + t], a2 = A2[b * D + t], gg = g[t];
    am[t] = gg * a1 + be[t];
    float var = gg * gg * (a2 - a1 * a1);
    as_[t] = sqrtf(fmaxf(var, EPS_STAT));
  }
  __syncthreads();
  float s = fcb[t], fq = 0.f;
  const float* wr = fcw + t * 2 * D;
  const float* qr = fcqw + t * D;
  for (int d = 0; d < D; ++d) {
    s += wr[d] * am[d] + wr[D + d] * as_[d];
    fq += qr[d] * am[d];
  }
  skip_i[b * D + t] = s;
  fcq[b * D + t] = fq;
}

// ---- fused FFN (layer 0 only; layer-1 FFN is dead code w.r.t. the output) ----
// Round-6 measured-best form: MT=64, 16x16 MFMA, 8-deep weight prefetch,
// vectorized stage-1, LN partials aliased into us front. 180.4 us, VGPR 56.
constexpr int MT = 64;

#define GEMM1_HALF(H0, ACC)                                                          \
  {                                                                                  \
    const unsigned short* wp0 = w1b + (size_t)((H0) + lr) * D + lq * 8;              \
    const unsigned short* wp1 = wp0 + 16 * D;                                        \
    short8 wr0[8], wr1[8];                                                           \
    _Pragma("unroll")                                                                \
    for (int kk = 0; kk < 8; ++kk) {                                                 \
      wr0[kk] = *(const short8*)(wp0 + kk * 32);                                     \
      wr1[kk] = *(const short8*)(wp1 + kk * 32);                                     \
    }                                                                                \
    int abase = lq * 512 + lr * 8;                                                   \
    _Pragma("unroll")                                                                \
    for (int kk = 0; kk < 8; ++kk) {                                                 \
      int nb = abase + kk * 2048;                                                    \
      short8 bf0 = *(const short8*)&us[nb];                                          \
      short8 bf1 = *(const short8*)&us[nb + 128];                                    \
      short8 bf2 = *(const short8*)&us[nb + 256];                                    \
      short8 bf3 = *(const short8*)&us[nb + 384];                                    \
      ACC[0][0] = __builtin_amdgcn_mfma_f32_16x16x32_bf16(wr0[kk], bf0, ACC[0][0],0,0,0);\
      ACC[0][1] = __builtin_amdgcn_mfma_f32_16x16x32_bf16(wr0[kk], bf1, ACC[0][1],0,0,0);\
      ACC[0][2] = __builtin_amdgcn_mfma_f32_16x16x32_bf16(wr0[kk], bf2, ACC[0][2],0,0,0);\
      ACC[0][3] = __builtin_amdgcn_mfma_f32_16x16x32_bf16(wr0[kk], bf3, ACC[0][3],0,0,0);\
      ACC[1][0] = __builtin_amdgcn_mfma_f32_16x16x32_bf16(wr1[kk], bf0, ACC[1][0],0,0,0);\
      ACC[1][1] = __builtin_amdgcn_mfma_f32_16x16x32_bf16(wr1[kk], bf1, ACC[1][1],0,0,0);\
      ACC[1][2] = __builtin_amdgcn_mfma_f32_16x16x32_bf16(wr1[kk], bf2, ACC[1][2],0,0,0);\
      ACC[1][3] = __builtin_amdgcn_mfma_f32_16x16x32_bf16(wr1[kk], bf3, ACC[1][3],0,0,0);\
    }                                                                                \
  }

#define H1_WRITE(H0, ACC)                                                            \
  {                                                                                  \
    _Pragma("unroll")                                                                \
    for (int mh = 0; mh < 2; ++mh) {                                                 \
      int hb = (H0) + mh * 16 + lq * 4;                                              \
      float b10 = b1[hb], b11 = b1[hb + 1], b12 = b1[hb + 2], b13 = b1[hb + 3];      \
      int grp = ((hb >> 3) + 32) & 63;                                               \
      int jh0 = hb & 7;                                                              \
      _Pragma("unroll")                                                              \
      for (int nt = 0; nt < 4; ++nt) {                                               \
        int tok = nt * 16 + lr;                                                      \
        uint2 pk;                                                                    \
        pk.x = pk2bf(fmaxf(ACC[mh][nt][0] + b10, 0.f),                               \
                     fmaxf(ACC[mh][nt][1] + b11, 0.f));                              \
        pk.y = pk2bf(fmaxf(ACC[mh][nt][2] + b12, 0.f),                               \
                     fmaxf(ACC[mh][nt][3] + b13, 0.f));                              \
        *(uint2*)&us[grp * 512 + tok * 8 + jh0] = pk;                                \
      }                                                                              \
    }                                                                                \
  }

#define GEMM2_HALF(M0, ACC2)                                                         \
  {                                                                                  \
    const unsigned short* wp = w2b + (size_t)((M0) + lr) * H + lq * 8;               \
    short8 wrg[16];                                                                  \
    _Pragma("unroll")                                                                \
    for (int kk = 0; kk < 16; ++kk) wrg[kk] = *(const short8*)(wp + kk * 32);        \
    _Pragma("unroll")                                                                \
    for (int kk = 0; kk < 16; ++kk) {                                                \
      int hb = ((kk * 4 + lq + 32) & 63) * 512 + lr * 8;                             \
      short8 hf0 = *(const short8*)&us[hb];                                          \
      short8 hf1 = *(const short8*)&us[hb + 128];                                    \
      short8 hf2 = *(const short8*)&us[hb + 256];                                    \
      short8 hf3 = *(const short8*)&us[hb + 384];                                    \
      ACC2[0] = __builtin_amdgcn_mfma_f32_16x16x32_bf16(wrg[kk], hf0, ACC2[0], 0, 0, 0);\
      ACC2[1] = __builtin_amdgcn_mfma_f32_16x16x32_bf16(wrg[kk], hf1, ACC2[1], 0, 0, 0);\
      ACC2[2] = __builtin_amdgcn_mfma_f32_16x16x32_bf16(wrg[kk], hf2, ACC2[2], 0, 0, 0);\
      ACC2[3] = __builtin_amdgcn_mfma_f32_16x16x32_bf16(wrg[kk], hf3, ACC2[3], 0, 0, 0);\
    }                                                                                \
  }

#define EPI_HALF(M0, ACC2)                                                           \
  {                                                                                  \
    _Pragma("unroll")                                                                \
    for (int i = 0; i < 4; ++i) {                                                    \
      int d = (M0) + lq * 4 + i;                                                     \
      float bb = b2_s[d] + fcq_s[d];                                                 \
      size_t rowoff = ((size_t)b * D + d) * L + l0;                                  \
      _Pragma("unroll")                                                              \
      for (int nt = 0; nt < 4; ++nt) {                                               \
        int tok = nt * 16 + lr;                                                      \
        dst[rowoff + tok] = ACC2[nt][i] + bb + src[rowoff + tok];                    \
      }                                                                              \
    }                                                                                \
  }

__global__ __launch_bounds__(512, 4) void k_ffn(
    const float* src, float* dst, const float* __restrict__ fcq,
    const unsigned short* __restrict__ w1b, const float* __restrict__ b1,
    const unsigned short* __restrict__ w2b, const float* __restrict__ b2,
    const float* __restrict__ g, const float* __restrict__ be) {
  __shared__ __align__(16) unsigned short us[32768];   // 64 KB
  __shared__ float fcq_s[D], g_s[D], be_s[D], b2_s[D];
  __shared__ __align__(16) float mu_s[MT], rs_s[MT];
  // LN partial sums alias front of us (dead before a_tile is packed)
  float* part1 = (float*)us;            // [32][64] floats = 8KB
  float* part2 = (float*)(us + 4096);   // next 8KB

  int blk = blockIdx.x;
  int b = blk >> 5;
  int l0 = (blk & 31) * MT;
  int tid = threadIdx.x;
  int lane4 = tid & 15, rg = tid >> 4;      // rg 0..31: d-rows rg*8..+7; 4 tokens each
  int wv = tid >> 6, lane = tid & 63, lr = lane & 15, lq = lane >> 4;

  if (tid < D) {
    fcq_s[tid] = fcq[b * D + tid];
    g_s[tid] = g[tid]; be_s[tid] = be[tid]; b2_s[tid] = b2[tid];
  }
  __syncthreads();

  // ---- stage 1: vectorized load (8x float4), add fcq, token LN stats ----
  const float* vrow = src + ((size_t)b * D + rg * 8) * L + l0 + lane4 * 4;
  float4_ vv[8];
  float4_ s1 = {0.f, 0.f, 0.f, 0.f}, s2 = {0.f, 0.f, 0.f, 0.f};
  #pragma unroll
  for (int j = 0; j < 8; ++j) {
    float4_ x = *(const float4_*)&vrow[(size_t)j * L];
    x = x + fcq_s[rg * 8 + j];
    vv[j] = x; s1 += x; s2 += x * x;
  }
  *(float4_*)&part1[rg * 64 + lane4 * 4] = s1;
  *(float4_*)&part2[rg * 64 + lane4 * 4] = s2;
  __syncthreads();
  if (tid < MT) {
    float a = 0.f, c = 0.f;
    #pragma unroll
    for (int q = 0; q < 32; ++q) { a += part1[q * 64 + tid]; c += part2[q * 64 + tid]; }
    float mu = a * (1.f / D);
    float var = c * (1.f / D) - mu * mu;
    mu_s[tid] = mu; rs_s[tid] = rsqrtf(var + EPS_LN);
  }
  __syncthreads();                // part reads done; pack may overwrite
  {
    float4_ mu4 = *(const float4_*)&mu_s[lane4 * 4];
    float4_ rs4 = *(const float4_*)&rs_s[lane4 * 4];
    #pragma unroll
    for (int c = 0; c < 4; ++c) {
      uint4 pw;
      unsigned* pp = &pw.x;
      #pragma unroll
      for (int jj = 0; jj < 4; ++jj) {
        int d0 = rg * 8 + jj * 2;
        pp[jj] = pk2bf((vv[jj * 2][c]     - mu4[c]) * rs4[c] * g_s[d0]     + be_s[d0],
                       (vv[jj * 2 + 1][c] - mu4[c]) * rs4[c] * g_s[d0 + 1] + be_s[d0 + 1]);
      }
      *(uint4*)&us[(rg * 64 + lane4 * 4 + c) * 8] = pw;
    }
  }
  __syncthreads();

  float4_ zero = {0.f, 0.f, 0.f, 0.f};

  // ---- GEMM1 phase A: h in [wv*32, +32) -> h1 upper ----
  {
    float4_ accA[2][4];
    #pragma unroll
    for (int i = 0; i < 2; ++i)
      #pragma unroll
      for (int j = 0; j < 4; ++j) accA[i][j] = zero;
    GEMM1_HALF(wv * 32, accA)
    H1_WRITE(wv * 32, accA)
  }
  // ---- GEMM1 phase B: h in [256+wv*32, +32) -> h1 lower (alias a_tile) ----
  {
    float4_ accB[2][4];
    #pragma unroll
    for (int i = 0; i < 2; ++i)
      #pragma unroll
      for (int j = 0; j < 4; ++j) accB[i][j] = zero;
    GEMM1_HALF(256 + wv * 32, accB)
    __syncthreads();               // all a_tile reads done (WAR)
    H1_WRITE(256 + wv * 32, accB)
  }
  __syncthreads();                 // h1 fully visible

  // ---- GEMM2 phases (split, round-1 form) ----
  {
    float4_ acc2[4];
    #pragma unroll
    for (int j = 0; j < 4; ++j) acc2[j] = zero;
    GEMM2_HALF(wv * 16, acc2)
    EPI_HALF(wv * 16, acc2)
  }
  {
    float4_ acc2[4];
    #pragma unroll
    for (int j = 0; j < 4; ++j) acc2[j] = zero;
    GEMM2_HALF(128 + wv * 16, acc2)
    EPI_HALF(128 + wv * 16, acc2)
  }
}

// ---- final: y = relu(skip0+skip1); batchnorm over B per channel d ----
__global__ void k_bn(const float* __restrict__ s0, const float* __restrict__ s1,
                     float* __restrict__ out) {
  int d = threadIdx.x;
  float s = 0.f, q = 0.f;
  for (int b = 0; b < B; ++b) {
    float y = fmaxf(s0[b * D + d] + s1[b * D + d], 0.f);
    s += y; q += y * y;
  }
  float mu = s * (1.f / B);
  float var = q * (1.f / B) - mu * mu;
  float rs = rsqrtf(var + EPS_BN);
  for (int b = 0; b < B; ++b) {
    float y = fmaxf(s0[b * D + d] + s1[b * D + d], 0.f);
    out[b * D + d] = (y - mu) * rs;
  }
}

extern "C" void kernel_launch(void* const* d_in, const int* in_sizes, int n_in,
                              void* d_out, int out_size, void* d_ws, size_t ws_size,
                              hipStream_t stream) {
  const float* x    = (const float*)d_in[0];
  const float* wk   = (const float*)d_in[1];
  const float* wq   = (const float*)d_in[2];
  const float* fcqw = (const float*)d_in[3];
  const float* fcw  = (const float*)d_in[4];
  const float* fcb  = (const float*)d_in[5];
  const float* ag   = (const float*)d_in[6];
  const float* abt  = (const float*)d_in[7];
  const float* w1   = (const float*)d_in[8];
  const float* b1   = (const float*)d_in[9];
  const float* w2   = (const float*)d_in[10];
  const float* b2   = (const float*)d_in[11];
  const float* fg   = (const float*)d_in[12];
  const float* fb   = (const float*)d_in[13];
  float* out = (float*)d_out;

  char* p = (char*)d_ws;
  float* v_ws = (float*)p;  p += (size_t)B * D * L * 4;
  float* m    = (float*)p;  p += (size_t)B * L * 4;
  float* r    = (float*)p;  p += (size_t)B * L * 4;
  float* sc   = (float*)p;  p += (size_t)B * L * 4;
  float* S1p  = (float*)p;  p += (size_t)B * 32 * D * 4;
  float* S2p  = (float*)p;  p += (size_t)B * 32 * D * 4;
  float* gw   = (float*)p;  p += (size_t)B * D * 4;
  float* A1   = (float*)p;  p += (size_t)B * D * 4;
  float* A2   = (float*)p;  p += (size_t)B * D * 4;
  float* fcqv = (float*)p;  p += (size_t)B * D * 4;
  float* sk0  = (float*)p;  p += (size_t)B * D * 4;
  float* sk1  = (float*)p;  p += (size_t)B * D * 4;
  unsigned short* w1b = (unsigned short*)p; p += (size_t)H * D * 2;
  unsigned short* w2b = (unsigned short*)p; p += (size_t)D * H * 2;

  // layer-1 FFN weights never needed (its output v is dead in the reference)
  k_convw<<<256, 256, 0, stream>>>(w1, w2, w1b, w2b);

  for (int i = 0; i < 2; ++i) {
    const float* src = (i == 0) ? x : v_ws;
    k_pass1<<<B * 32, 512, 0, stream>>>(src, m, r, S1p, S2p);
    k_qproj<<<B, 256, 0, stream>>>(S1p, S2p, ag + i * D, abt + i * D,
                                   wq + (size_t)i * KP * 2 * D,
                                   wk + (size_t)i * KP * D, gw);
    k_scores<<<B * L / 512, 256, 0, stream>>>(src, m, r, gw, sc);
    k_redw<<<B * 8, 256, 0, stream>>>(src, m, r, sc, A1, A2);
    k_skip<<<B, 256, 0, stream>>>(A1, A2, ag + i * D, abt + i * D,
                                  fcw + (size_t)i * D * 2 * D, fcb + i * D,
                                  fcqw + (size_t)i * D * D,
                                  (i == 0) ? sk0 : sk1, fcqv);
    if (i == 0) {
      // layer-1's FFN output v is never consumed (only skip_sum reaches the
      // output), so the FFN runs for layer 0 only.
      k_ffn<<<B * (L / MT), 512, 0, stream>>>(src, v_ws, fcqv,
                                              w1b, b1, w2b, b2, fg, fb);
    }
  }
  k_bn<<<1, 256, 0, stream>>>(sk0, sk1, out);
}

// Round 10
// 599.443 us; speedup vs baseline: 1.3427x; 1.0333x over previous
//
#include <hip/hip_runtime.h>
#include <hip/hip_bf16.h>

#define DEV __device__ __forceinline__

constexpr int B = 64, D = 256, L = 2048, H = 512, KP = 128;
constexpr float EPS_LN = 1e-6f, EPS_STAT = 1e-10f, EPS_BN = 1e-5f;
constexpr float SCALE = 0.088388347648318447f; // 1/sqrt(128)

typedef __attribute__((ext_vector_type(8))) short short8;
typedef __attribute__((ext_vector_type(4))) float float4_;

DEV unsigned short f2bf(float x) {
  unsigned u = __builtin_bit_cast(unsigned, x);
  u += 0x7fffu + ((u >> 16) & 1u);           // RNE
  return (unsigned short)(u >> 16);
}

DEV unsigned pk2bf(float a, float b) {       // two RNE cvts packed into a dword
  return (unsigned)f2bf(a) | ((unsigned)f2bf(b) << 16);
}

DEV float wred(float x) {
  #pragma unroll
  for (int o = 32; o > 0; o >>= 1) x += __shfl_down(x, o, 64);
  return x;
}
DEV float wredmax(float x) {
  #pragma unroll
  for (int o = 32; o > 0; o >>= 1) x = fmaxf(x, __shfl_down(x, o, 64));
  return x;
}

// ---- convert w1/w2 (layer 0 only; layer-1 FFN is dead code) ----
__global__ void k_convw(const float* __restrict__ w1, const float* __restrict__ w2,
                        unsigned short* __restrict__ w1b, unsigned short* __restrict__ w2b) {
  int n = H * D;
  for (int i = blockIdx.x * blockDim.x + threadIdx.x; i < n; i += gridDim.x * blockDim.x) {
    w1b[i] = f2bf(w1[i]);
    w2b[i] = f2bf(w2[i]);
  }
}

// ---- P1 v2: token-LN stats + per-(b,d,tile) sums, register-direct ----
// No ut transpose: S1p/S2p computed from register vv[] via 16-lane shfl_xor
// reduce. LDS 16.8KB -> 4 blocks/CU (was 66.5KB -> 2).
__global__ __launch_bounds__(512, 4) void k_pass1(
    const float* __restrict__ v, float* __restrict__ m, float* __restrict__ r,
    float* __restrict__ S1p, float* __restrict__ S2p) {
  __shared__ float part1[32 * 64], part2[32 * 64];   // 16 KB
  __shared__ __align__(16) float mu_s[64], rs_s[64];

  int blk = blockIdx.x;
  int b = blk >> 5, tile = blk & 31, l0 = tile * 64;
  int tid = threadIdx.x;
  int lane4 = tid & 15, rg = tid >> 4;      // rg 0..31: 8 d-rows; lane4: 4 tokens

  const float* vrow = v + ((size_t)b * D + rg * 8) * L + l0 + lane4 * 4;
  float4_ vv[8];
  float4_ s1 = {0.f, 0.f, 0.f, 0.f}, s2 = {0.f, 0.f, 0.f, 0.f};
  #pragma unroll
  for (int j = 0; j < 8; ++j) {
    float4_ x = *(const float4_*)&vrow[(size_t)j * L];
    vv[j] = x; s1 += x; s2 += x * x;
  }
  *(float4_*)&part1[rg * 64 + lane4 * 4] = s1;
  *(float4_*)&part2[rg * 64 + lane4 * 4] = s2;
  __syncthreads();
  if (tid < 64) {
    float a = 0.f, c = 0.f;
    #pragma unroll
    for (int q = 0; q < 32; ++q) { a += part1[q * 64 + tid]; c += part2[q * 64 + tid]; }
    float mu = a * (1.f / D);
    float var = c * (1.f / D) - mu * mu;
    float rsq = rsqrtf(var + EPS_LN);
    mu_s[tid] = mu; rs_s[tid] = rsq;
    m[b * L + l0 + tid] = mu;
    r[b * L + l0 + tid] = rsq;
  }
  __syncthreads();
  {
    float4_ mu4 = *(const float4_*)&mu_s[lane4 * 4];
    float4_ rs4 = *(const float4_*)&rs_s[lane4 * 4];
    size_t obase = ((size_t)b * 32 + tile) * D + rg * 8;
    #pragma unroll
    for (int j = 0; j < 8; ++j) {
      float4_ u = (vv[j] - mu4) * rs4;
      float a1 = u[0] + u[1] + u[2] + u[3];
      float a2 = u[0] * u[0] + u[1] * u[1] + u[2] * u[2] + u[3] * u[3];
      #pragma unroll
      for (int o = 1; o < 16; o <<= 1) {     // reduce over the 16 token-lanes
        a1 += __shfl_xor(a1, o, 64);
        a2 += __shfl_xor(a2, o, 64);
      }
      if (lane4 == 0) { S1p[obase + j] = a1; S2p[obase + j] = a2; }
    }
  }
}

// ---- per-b: reduce partials -> mu/sd over L -> q -> gw (+ G = sum_d gw) ----
__global__ void k_qproj(const float* __restrict__ S1p, const float* __restrict__ S2p,
                        const float* __restrict__ g, const float* __restrict__ be,
                        const float* __restrict__ wq, const float* __restrict__ wk,
                        float* __restrict__ gw, float* __restrict__ Gg) {
  __shared__ float cat[2 * D];
  __shared__ float qs[KP];
  __shared__ float gsum[4];
  int b = blockIdx.x, t = threadIdx.x;  // 256 threads
  {
    float s1 = 0.f, s2 = 0.f;
    for (int k = 0; k < 32; ++k) {
      s1 += S1p[((size_t)b * 32 + k) * D + t];
      s2 += S2p[((size_t)b * 32 + k) * D + t];
    }
    s1 *= (1.f / L); s2 *= (1.f / L);
    float gg = g[t];
    cat[t] = gg * s1 + be[t];
    float var = gg * gg * (s2 - s1 * s1);
    cat[D + t] = sqrtf(fmaxf(var, EPS_STAT));
  }
  __syncthreads();
  if (t < KP) {
    float s = 0.f;
    const float* wr = wq + t * 2 * D;
    for (int e = 0; e < 2 * D; ++e) s += cat[e] * wr[e];
    qs[t] = s;
  }
  __syncthreads();
  {
    float s = 0.f;
    for (int k = 0; k < KP; ++k) s += wk[k * D + t] * qs[k];
    float gwv = g[t] * SCALE * s;  // beta const dropped (softmax-invariant)
    gw[b * D + t] = gwv;
    float gs = wred(gwv);
    if ((t & 63) == 0) gsum[t >> 6] = gs;
  }
  __syncthreads();
  if (t == 0) Gg[b] = gsum[0] + gsum[1] + gsum[2] + gsum[3];
}

// ---- scores v2: sc = r*(sum_d v*g - m*G); 2-way d-split, 512-thr blocks ----
__global__ __launch_bounds__(512) void k_scores(
    const float* __restrict__ v, const float* __restrict__ m,
    const float* __restrict__ r, const float* __restrict__ gw,
    const float* __restrict__ Gg, float* __restrict__ sc) {
  __shared__ float gws[D];
  __shared__ float sh[256];
  int blk = blockIdx.x;
  int b = blk >> 3, l0 = (blk & 7) * 256;
  int tid = threadIdx.x, lt = tid & 255, dh = tid >> 8;   // dh: which 128-d half
  if (tid < D) gws[tid] = gw[b * D + tid];
  __syncthreads();
  int l = l0 + lt;
  const float* p = v + ((size_t)b * D + dh * 128) * L + l;
  float s = 0.f;
  #pragma unroll 8
  for (int d = 0; d < 128; ++d) s += p[(size_t)d * L] * gws[dh * 128 + d];
  if (dh == 1) sh[lt] = s;
  __syncthreads();
  if (dh == 0) {
    float tot = s + sh[lt];
    sc[b * L + l] = r[b * L + l] * (tot - m[b * L + l] * Gg[b]);
  }
}

// ---- softmax (in-block recompute) + weighted stats; 16 d-rows per block ----
__global__ __launch_bounds__(256) void k_redw(
    const float* __restrict__ v, const float* __restrict__ m, const float* __restrict__ r,
    const float* __restrict__ sc, float* __restrict__ A1, float* __restrict__ A2) {
  __shared__ float ws[L];
  __shared__ float ms[L], rs[L];
  __shared__ float red[4];
  int blk = blockIdx.x;
  int b = blk >> 4, dt = (blk & 15) * 16;
  int tid = threadIdx.x, wv = tid >> 6, lane = tid & 63;

  float xc[8];
  float mx = -1e30f;
  #pragma unroll
  for (int k = 0; k < 8; ++k) {
    float x = sc[b * L + tid + k * 256];
    xc[k] = x; mx = fmaxf(mx, x);
  }
  mx = wredmax(mx);
  if (lane == 0) red[wv] = mx;
  __syncthreads();
  mx = fmaxf(fmaxf(red[0], red[1]), fmaxf(red[2], red[3]));
  float sm = 0.f;
  #pragma unroll
  for (int k = 0; k < 8; ++k) { float e = __expf(xc[k] - mx); xc[k] = e; sm += e; }
  sm = wred(sm);
  __syncthreads();
  if (lane == 0) red[wv] = sm;
  __syncthreads();
  float inv = 1.f / (red[0] + red[1] + red[2] + red[3]);
  #pragma unroll
  for (int k = 0; k < 8; ++k) ws[tid + k * 256] = xc[k] * inv;
  for (int l = tid; l < L; l += 256) { ms[l] = m[b * L + l]; rs[l] = r[b * L + l]; }
  __syncthreads();

  for (int j = 0; j < 4; ++j) {
    int d = dt + wv * 4 + j;
    const float* row = v + ((size_t)b * D + d) * L;
    float a1 = 0.f, a2 = 0.f;
    #pragma unroll
    for (int k2 = 0; k2 < 8; ++k2) {
      int l = lane * 4 + k2 * 256;
      float4_ x4 = *(const float4_*)&row[l];
      #pragma unroll
      for (int i = 0; i < 4; ++i) {
        float u = (x4[i] - ms[l + i]) * rs[l + i];
        float w = ws[l + i];
        a1 += w * u; a2 += w * u * u;
      }
    }
    a1 = wred(a1); a2 = wred(a2);
    if (lane == 0) { A1[b * D + d] = a1; A2[b * D + d] = a2; }
  }
}

// ---- per-b: att_mean/std -> skip (this layer) + fcq ----
__global__ void k_skip(const float* __restrict__ A1, const float* __restrict__ A2,
                       const float* __restrict__ g, const float* __restrict__ be,
                       const float* __restrict__ fcw, const float* __restrict__ fcb,
                       const float* __restrict__ fcqw,
                       float* __restrict__ skip_i, float* __restrict__ fcq) {
  __shared__ float am[D], as_[D];
  int b = blockIdx.x, t = threadIdx.x;
  {
    float a1 = A1[b * D + t], a2 = A2[b * D + t], gg = g[t];
    am[t] = gg * a1 + be[t];
    float var = gg * gg * (a2 - a1 * a1);
    as_[t] = sqrtf(fmaxf(var, EPS_STAT));
  }
  __syncthreads();
  float s = fcb[t], fq = 0.f;
  const float* wr = fcw + t * 2 * D;
  const float* qr = fcqw + t * D;
  for (int d = 0; d < D; ++d) {
    s += wr[d] * am[d] + wr[D + d] * as_[d];
    fq += qr[d] * am[d];
  }
  skip_i[b * D + t] = s;
  fcq[b * D + t] = fq;
}

// ---- fused FFN (layer 0 only): round-6 measured-best form, unchanged ----
constexpr int MT = 64;

#define GEMM1_HALF(H0, ACC)                                                          \
  {                                                                                  \
    const unsigned short* wp0 = w1b + (size_t)((H0) + lr) * D + lq * 8;              \
    const unsigned short* wp1 = wp0 + 16 * D;                                        \
    short8 wr0[8], wr1[8];                                                           \
    _Pragma("unroll")                                                                \
    for (int kk = 0; kk < 8; ++kk) {                                                 \
      wr0[kk] = *(const short8*)(wp0 + kk * 32);                                     \
      wr1[kk] = *(const short8*)(wp1 + kk * 32);                                     \
    }                                                                                \
    int abase = lq * 512 + lr * 8;                                                   \
    _Pragma("unroll")                                                                \
    for (int kk = 0; kk < 8; ++kk) {                                                 \
      int nb = abase + kk * 2048;                                                    \
      short8 bf0 = *(const short8*)&us[nb];                                          \
      short8 bf1 = *(const short8*)&us[nb + 128];                                    \
      short8 bf2 = *(const short8*)&us[nb + 256];                                    \
      short8 bf3 = *(const short8*)&us[nb + 384];                                    \
      ACC[0][0] = __builtin_amdgcn_mfma_f32_16x16x32_bf16(wr0[kk], bf0, ACC[0][0],0,0,0);\
      ACC[0][1] = __builtin_amdgcn_mfma_f32_16x16x32_bf16(wr0[kk], bf1, ACC[0][1],0,0,0);\
      ACC[0][2] = __builtin_amdgcn_mfma_f32_16x16x32_bf16(wr0[kk], bf2, ACC[0][2],0,0,0);\
      ACC[0][3] = __builtin_amdgcn_mfma_f32_16x16x32_bf16(wr0[kk], bf3, ACC[0][3],0,0,0);\
      ACC[1][0] = __builtin_amdgcn_mfma_f32_16x16x32_bf16(wr1[kk], bf0, ACC[1][0],0,0,0);\
      ACC[1][1] = __builtin_amdgcn_mfma_f32_16x16x32_bf16(wr1[kk], bf1, ACC[1][1],0,0,0);\
      ACC[1][2] = __builtin_amdgcn_mfma_f32_16x16x32_bf16(wr1[kk], bf2, ACC[1][2],0,0,0);\
      ACC[1][3] = __builtin_amdgcn_mfma_f32_16x16x32_bf16(wr1[kk], bf3, ACC[1][3],0,0,0);\
    }                                                                                \
  }

#define H1_WRITE(H0, ACC)                                                            \
  {                                                                                  \
    _Pragma("unroll")                                                                \
    for (int mh = 0; mh < 2; ++mh) {                                                 \
      int hb = (H0) + mh * 16 + lq * 4;                                              \
      float b10 = b1[hb], b11 = b1[hb + 1], b12 = b1[hb + 2], b13 = b1[hb + 3];      \
      int grp = ((hb >> 3) + 32) & 63;                                               \
      int jh0 = hb & 7;                                                              \
      _Pragma("unroll")                                                              \
      for (int nt = 0; nt < 4; ++nt) {                                               \
        int tok = nt * 16 + lr;                                                      \
        uint2 pk;                                                                    \
        pk.x = pk2bf(fmaxf(ACC[mh][nt][0] + b10, 0.f),                               \
                     fmaxf(ACC[mh][nt][1] + b11, 0.f));                              \
        pk.y = pk2bf(fmaxf(ACC[mh][nt][2] + b12, 0.f),                               \
                     fmaxf(ACC[mh][nt][3] + b13, 0.f));                              \
        *(uint2*)&us[grp * 512 + tok * 8 + jh0] = pk;                                \
      }                                                                              \
    }                                                                                \
  }

#define GEMM2_HALF(M0, ACC2)                                                         \
  {                                                                                  \
    const unsigned short* wp = w2b + (size_t)((M0) + lr) * H + lq * 8;               \
    short8 wrg[16];                                                                  \
    _Pragma("unroll")                                                                \
    for (int kk = 0; kk < 16; ++kk) wrg[kk] = *(const short8*)(wp + kk * 32);        \
    _Pragma("unroll")                                                                \
    for (int kk = 0; kk < 16; ++kk) {                                                \
      int hb = ((kk * 4 + lq + 32) & 63) * 512 + lr * 8;                             \
      short8 hf0 = *(const short8*)&us[hb];                                          \
      short8 hf1 = *(const short8*)&us[hb + 128];                                    \
      short8 hf2 = *(const short8*)&us[hb + 256];                                    \
      short8 hf3 = *(const short8*)&us[hb + 384];                                    \
      ACC2[0] = __builtin_amdgcn_mfma_f32_16x16x32_bf16(wrg[kk], hf0, ACC2[0], 0, 0, 0);\
      ACC2[1] = __builtin_amdgcn_mfma_f32_16x16x32_bf16(wrg[kk], hf1, ACC2[1], 0, 0, 0);\
      ACC2[2] = __builtin_amdgcn_mfma_f32_16x16x32_bf16(wrg[kk], hf2, ACC2[2], 0, 0, 0);\
      ACC2[3] = __builtin_amdgcn_mfma_f32_16x16x32_bf16(wrg[kk], hf3, ACC2[3], 0, 0, 0);\
    }                                                                                \
  }

#define EPI_HALF(M0, ACC2)                                                           \
  {                                                                                  \
    _Pragma("unroll")                                                                \
    for (int i = 0; i < 4; ++i) {                                                    \
      int d = (M0) + lq * 4 + i;                                                     \
      float bb = b2_s[d] + fcq_s[d];                                                 \
      size_t rowoff = ((size_t)b * D + d) * L + l0;                                  \
      _Pragma("unroll")                                                              \
      for (int nt = 0; nt < 4; ++nt) {                                               \
        int tok = nt * 16 + lr;                                                      \
        dst[rowoff + tok] = ACC2[nt][i] + bb + src[rowoff + tok];                    \
      }                                                                              \
    }                                                                                \
  }

__global__ __launch_bounds__(512, 4) void k_ffn(
    const float* src, float* dst, const float* __restrict__ fcq,
    const unsigned short* __restrict__ w1b, const float* __restrict__ b1,
    const unsigned short* __restrict__ w2b, const float* __restrict__ b2,
    const float* __restrict__ g, const float* __restrict__ be) {
  __shared__ __align__(16) unsigned short us[32768];   // 64 KB
  __shared__ float fcq_s[D], g_s[D], be_s[D], b2_s[D];
  __shared__ __align__(16) float mu_s[MT], rs_s[MT];
  float* part1 = (float*)us;            // [32][64] floats = 8KB (dead before pack)
  float* part2 = (float*)(us + 4096);   // next 8KB

  int blk = blockIdx.x;
  int b = blk >> 5;
  int l0 = (blk & 31) * MT;
  int tid = threadIdx.x;
  int lane4 = tid & 15, rg = tid >> 4;
  int wv = tid >> 6, lane = tid & 63, lr = lane & 15, lq = lane >> 4;

  if (tid < D) {
    fcq_s[tid] = fcq[b * D + tid];
    g_s[tid] = g[tid]; be_s[tid] = be[tid]; b2_s[tid] = b2[tid];
  }
  __syncthreads();

  const float* vrow = src + ((size_t)b * D + rg * 8) * L + l0 + lane4 * 4;
  float4_ vv[8];
  float4_ s1 = {0.f, 0.f, 0.f, 0.f}, s2 = {0.f, 0.f, 0.f, 0.f};
  #pragma unroll
  for (int j = 0; j < 8; ++j) {
    float4_ x = *(const float4_*)&vrow[(size_t)j * L];
    x = x + fcq_s[rg * 8 + j];
    vv[j] = x; s1 += x; s2 += x * x;
  }
  *(float4_*)&part1[rg * 64 + lane4 * 4] = s1;
  *(float4_*)&part2[rg * 64 + lane4 * 4] = s2;
  __syncthreads();
  if (tid < MT) {
    float a = 0.f, c = 0.f;
    #pragma unroll
    for (int q = 0; q < 32; ++q) { a += part1[q * 64 + tid]; c += part2[q * 64 + tid]; }
    float mu = a * (1.f / D);
    float var = c * (1.f / D) - mu * mu;
    mu_s[tid] = mu; rs_s[tid] = rsqrtf(var + EPS_LN);
  }
  __syncthreads();
  {
    float4_ mu4 = *(const float4_*)&mu_s[lane4 * 4];
    float4_ rs4 = *(const float4_*)&rs_s[lane4 * 4];
    #pragma unroll
    for (int c = 0; c < 4; ++c) {
      uint4 pw;
      unsigned* pp = &pw.x;
      #pragma unroll
      for (int jj = 0; jj < 4; ++jj) {
        int d0 = rg * 8 + jj * 2;
        pp[jj] = pk2bf((vv[jj * 2][c]     - mu4[c]) * rs4[c] * g_s[d0]     + be_s[d0],
                       (vv[jj * 2 + 1][c] - mu4[c]) * rs4[c] * g_s[d0 + 1] + be_s[d0 + 1]);
      }
      *(uint4*)&us[(rg * 64 + lane4 * 4 + c) * 8] = pw;
    }
  }
  __syncthreads();

  float4_ zero = {0.f, 0.f, 0.f, 0.f};

  {
    float4_ accA[2][4];
    #pragma unroll
    for (int i = 0; i < 2; ++i)
      #pragma unroll
      for (int j = 0; j < 4; ++j) accA[i][j] = zero;
    GEMM1_HALF(wv * 32, accA)
    H1_WRITE(wv * 32, accA)
  }
  {
    float4_ accB[2][4];
    #pragma unroll
    for (int i = 0; i < 2; ++i)
      #pragma unroll
      for (int j = 0; j < 4; ++j) accB[i][j] = zero;
    GEMM1_HALF(256 + wv * 32, accB)
    __syncthreads();               // all a_tile reads done (WAR)
    H1_WRITE(256 + wv * 32, accB)
  }
  __syncthreads();                 // h1 fully visible

  {
    float4_ acc2[4];
    #pragma unroll
    for (int j = 0; j < 4; ++j) acc2[j] = zero;
    GEMM2_HALF(wv * 16, acc2)
    EPI_HALF(wv * 16, acc2)
  }
  {
    float4_ acc2[4];
    #pragma unroll
    for (int j = 0; j < 4; ++j) acc2[j] = zero;
    GEMM2_HALF(128 + wv * 16, acc2)
    EPI_HALF(128 + wv * 16, acc2)
  }
}

// ---- final: y = relu(skip0+skip1); batchnorm over B per channel d ----
__global__ void k_bn(const float* __restrict__ s0, const float* __restrict__ s1,
                     float* __restrict__ out) {
  int d = threadIdx.x;
  float s = 0.f, q = 0.f;
  for (int b = 0; b < B; ++b) {
    float y = fmaxf(s0[b * D + d] + s1[b * D + d], 0.f);
    s += y; q += y * y;
  }
  float mu = s * (1.f / B);
  float var = q * (1.f / B) - mu * mu;
  float rs = rsqrtf(var + EPS_BN);
  for (int b = 0; b < B; ++b) {
    float y = fmaxf(s0[b * D + d] + s1[b * D + d], 0.f);
    out[b * D + d] = (y - mu) * rs;
  }
}

extern "C" void kernel_launch(void* const* d_in, const int* in_sizes, int n_in,
                              void* d_out, int out_size, void* d_ws, size_t ws_size,
                              hipStream_t stream) {
  const float* x    = (const float*)d_in[0];
  const float* wk   = (const float*)d_in[1];
  const float* wq   = (const float*)d_in[2];
  const float* fcqw = (const float*)d_in[3];
  const float* fcw  = (const float*)d_in[4];
  const float* fcb  = (const float*)d_in[5];
  const float* ag   = (const float*)d_in[6];
  const float* abt  = (const float*)d_in[7];
  const float* w1   = (const float*)d_in[8];
  const float* b1   = (const float*)d_in[9];
  const float* w2   = (const float*)d_in[10];
  const float* b2   = (const float*)d_in[11];
  const float* fg   = (const float*)d_in[12];
  const float* fb   = (const float*)d_in[13];
  float* out = (float*)d_out;

  char* p = (char*)d_ws;
  float* v_ws = (float*)p;  p += (size_t)B * D * L * 4;
  float* m    = (float*)p;  p += (size_t)B * L * 4;
  float* r    = (float*)p;  p += (size_t)B * L * 4;
  float* sc   = (float*)p;  p += (size_t)B * L * 4;
  float* S1p  = (float*)p;  p += (size_t)B * 32 * D * 4;
  float* S2p  = (float*)p;  p += (size_t)B * 32 * D * 4;
  float* gw   = (float*)p;  p += (size_t)B * D * 4;
  float* A1   = (float*)p;  p += (size_t)B * D * 4;
  float* A2   = (float*)p;  p += (size_t)B * D * 4;
  float* fcqv = (float*)p;  p += (size_t)B * D * 4;
  float* sk0  = (float*)p;  p += (size_t)B * D * 4;
  float* sk1  = (float*)p;  p += (size_t)B * D * 4;
  float* Gg   = (float*)p;  p += (size_t)B * 4;
  unsigned short* w1b = (unsigned short*)p; p += (size_t)H * D * 2;
  unsigned short* w2b = (unsigned short*)p; p += (size_t)D * H * 2;

  // layer-1 FFN weights never needed (its output v is dead in the reference)
  k_convw<<<256, 256, 0, stream>>>(w1, w2, w1b, w2b);

  for (int i = 0; i < 2; ++i) {
    const float* src = (i == 0) ? x : v_ws;
    k_pass1<<<B * 32, 512, 0, stream>>>(src, m, r, S1p, S2p);
    k_qproj<<<B, 256, 0, stream>>>(S1p, S2p, ag + i * D, abt + i * D,
                                   wq + (size_t)i * KP * 2 * D,
                                   wk + (size_t)i * KP * D, gw, Gg);
    k_scores<<<B * 8, 512, 0, stream>>>(src, m, r, gw, Gg, sc);
    k_redw<<<B * 16, 256, 0, stream>>>(src, m, r, sc, A1, A2);
    k_skip<<<B, 256, 0, stream>>>(A1, A2, ag + i * D, abt + i * D,
                                  fcw + (size_t)i * D * 2 * D, fcb + i * D,
                                  fcqw + (size_t)i * D * D,
                                  (i == 0) ? sk0 : sk1, fcqv);
    if (i == 0) {
      // layer-1's FFN output v is never consumed (only skip_sum reaches the
      // output), so the FFN runs for layer 0 only.
      k_ffn<<<B * (L / MT), 512, 0, stream>>>(src, v_ws, fcqv,
                                              w1b, b1, w2b, b2, fg, fb);
    }
  }
  k_bn<<<1, 256, 0, stream>>>(sk0, sk1, out);
}

// Round 11
// 598.285 us; speedup vs baseline: 1.3453x; 1.0019x over previous
//
#include <hip/hip_runtime.h>
#include <hip/hip_bf16.h>

#define DEV __device__ __forceinline__

constexpr int B = 64, D = 256, L = 2048, H = 512, KP = 128;
constexpr float EPS_LN = 1e-6f, EPS_STAT = 1e-10f, EPS_BN = 1e-5f;
constexpr float SCALE = 0.088388347648318447f; // 1/sqrt(128)

typedef __attribute__((ext_vector_type(8))) short short8;
typedef __attribute__((ext_vector_type(4))) float float4_;

DEV unsigned short f2bf(float x) {
  unsigned u = __builtin_bit_cast(unsigned, x);
  u += 0x7fffu + ((u >> 16) & 1u);           // RNE
  return (unsigned short)(u >> 16);
}

DEV unsigned pk2bf(float a, float b) {       // two RNE cvts packed into a dword
  return (unsigned)f2bf(a) | ((unsigned)f2bf(b) << 16);
}

DEV float wred(float x) {
  #pragma unroll
  for (int o = 32; o > 0; o >>= 1) x += __shfl_down(x, o, 64);
  return x;
}
DEV float wredmax(float x) {
  #pragma unroll
  for (int o = 32; o > 0; o >>= 1) x = fmaxf(x, __shfl_down(x, o, 64));
  return x;
}

// ---- convert w1/w2 (layer 0 only; layer-1 FFN is dead code) ----
__global__ void k_convw(const float* __restrict__ w1, const float* __restrict__ w2,
                        unsigned short* __restrict__ w1b, unsigned short* __restrict__ w2b) {
  int n = H * D;
  for (int i = blockIdx.x * blockDim.x + threadIdx.x; i < n; i += gridDim.x * blockDim.x) {
    w1b[i] = f2bf(w1[i]);
    w2b[i] = f2bf(w2[i]);
  }
}

// ---- P1 v2 (layer 0 only): token-LN stats + per-(b,d,tile) sums ----
__global__ __launch_bounds__(512, 4) void k_pass1(
    const float* __restrict__ v, float* __restrict__ m, float* __restrict__ r,
    float* __restrict__ S1p, float* __restrict__ S2p) {
  __shared__ float part1[32 * 64], part2[32 * 64];   // 16 KB
  __shared__ __align__(16) float mu_s[64], rs_s[64];

  int blk = blockIdx.x;
  int b = blk >> 5, tile = blk & 31, l0 = tile * 64;
  int tid = threadIdx.x;
  int lane4 = tid & 15, rg = tid >> 4;      // rg 0..31: 8 d-rows; lane4: 4 tokens

  const float* vrow = v + ((size_t)b * D + rg * 8) * L + l0 + lane4 * 4;
  float4_ vv[8];
  float4_ s1 = {0.f, 0.f, 0.f, 0.f}, s2 = {0.f, 0.f, 0.f, 0.f};
  #pragma unroll
  for (int j = 0; j < 8; ++j) {
    float4_ x = *(const float4_*)&vrow[(size_t)j * L];
    vv[j] = x; s1 += x; s2 += x * x;
  }
  *(float4_*)&part1[rg * 64 + lane4 * 4] = s1;
  *(float4_*)&part2[rg * 64 + lane4 * 4] = s2;
  __syncthreads();
  if (tid < 64) {
    float a = 0.f, c = 0.f;
    #pragma unroll
    for (int q = 0; q < 32; ++q) { a += part1[q * 64 + tid]; c += part2[q * 64 + tid]; }
    float mu = a * (1.f / D);
    float var = c * (1.f / D) - mu * mu;
    float rsq = rsqrtf(var + EPS_LN);
    mu_s[tid] = mu; rs_s[tid] = rsq;
    m[b * L + l0 + tid] = mu;
    r[b * L + l0 + tid] = rsq;
  }
  __syncthreads();
  {
    float4_ mu4 = *(const float4_*)&mu_s[lane4 * 4];
    float4_ rs4 = *(const float4_*)&rs_s[lane4 * 4];
    size_t obase = ((size_t)b * 32 + tile) * D + rg * 8;
    #pragma unroll
    for (int j = 0; j < 8; ++j) {
      float4_ u = (vv[j] - mu4) * rs4;
      float a1 = u[0] + u[1] + u[2] + u[3];
      float a2 = u[0] * u[0] + u[1] * u[1] + u[2] * u[2] + u[3] * u[3];
      #pragma unroll
      for (int o = 1; o < 16; o <<= 1) {
        a1 += __shfl_xor(a1, o, 64);
        a2 += __shfl_xor(a2, o, 64);
      }
      if (lane4 == 0) { S1p[obase + j] = a1; S2p[obase + j] = a2; }
    }
  }
}

// ---- per-b: reduce partials -> mu/sd over L -> q -> gw (+ G = sum_d gw) ----
__global__ void k_qproj(const float* __restrict__ S1p, const float* __restrict__ S2p,
                        const float* __restrict__ g, const float* __restrict__ be,
                        const float* __restrict__ wq, const float* __restrict__ wk,
                        float* __restrict__ gw, float* __restrict__ Gg) {
  __shared__ float cat[2 * D];
  __shared__ float qs[KP];
  __shared__ float gsum[4];
  int b = blockIdx.x, t = threadIdx.x;  // 256 threads
  {
    float s1 = 0.f, s2 = 0.f;
    for (int k = 0; k < 32; ++k) {
      s1 += S1p[((size_t)b * 32 + k) * D + t];
      s2 += S2p[((size_t)b * 32 + k) * D + t];
    }
    s1 *= (1.f / L); s2 *= (1.f / L);
    float gg = g[t];
    cat[t] = gg * s1 + be[t];
    float var = gg * gg * (s2 - s1 * s1);
    cat[D + t] = sqrtf(fmaxf(var, EPS_STAT));
  }
  __syncthreads();
  if (t < KP) {
    float s = 0.f;
    const float* wr = wq + t * 2 * D;
    for (int e = 0; e < 2 * D; ++e) s += cat[e] * wr[e];
    qs[t] = s;
  }
  __syncthreads();
  {
    float s = 0.f;
    for (int k = 0; k < KP; ++k) s += wk[k * D + t] * qs[k];
    float gwv = g[t] * SCALE * s;  // beta const dropped (softmax-invariant)
    gw[b * D + t] = gwv;
    float gs = wred(gwv);
    if ((t & 63) == 0) gsum[t >> 6] = gs;
  }
  __syncthreads();
  if (t == 0) Gg[b] = gsum[0] + gsum[1] + gsum[2] + gsum[3];
}

// ---- scores v2: sc = r*(sum_d v*g - m*G); 2-way d-split, 512-thr blocks ----
__global__ __launch_bounds__(512) void k_scores(
    const float* __restrict__ v, const float* __restrict__ m,
    const float* __restrict__ r, const float* __restrict__ gw,
    const float* __restrict__ Gg, float* __restrict__ sc) {
  __shared__ float gws[D];
  __shared__ float sh[256];
  int blk = blockIdx.x;
  int b = blk >> 3, l0 = (blk & 7) * 256;
  int tid = threadIdx.x, lt = tid & 255, dh = tid >> 8;   // dh: which 128-d half
  if (tid < D) gws[tid] = gw[b * D + tid];
  __syncthreads();
  int l = l0 + lt;
  const float* p = v + ((size_t)b * D + dh * 128) * L + l;
  float s = 0.f;
  #pragma unroll 8
  for (int d = 0; d < 128; ++d) s += p[(size_t)d * L] * gws[dh * 128 + d];
  if (dh == 1) sh[lt] = s;
  __syncthreads();
  if (dh == 0) {
    float tot = s + sh[lt];
    sc[b * L + l] = r[b * L + l] * (tot - m[b * L + l] * Gg[b]);
  }
}

// ---- softmax (in-block recompute) + weighted stats; 16 d-rows per block ----
__global__ __launch_bounds__(256) void k_redw(
    const float* __restrict__ v, const float* __restrict__ m, const float* __restrict__ r,
    const float* __restrict__ sc, float* __restrict__ A1, float* __restrict__ A2) {
  __shared__ float ws[L];
  __shared__ float ms[L], rs[L];
  __shared__ float red[4];
  int blk = blockIdx.x;
  int b = blk >> 4, dt = (blk & 15) * 16;
  int tid = threadIdx.x, wv = tid >> 6, lane = tid & 63;

  float xc[8];
  float mx = -1e30f;
  #pragma unroll
  for (int k = 0; k < 8; ++k) {
    float x = sc[b * L + tid + k * 256];
    xc[k] = x; mx = fmaxf(mx, x);
  }
  mx = wredmax(mx);
  if (lane == 0) red[wv] = mx;
  __syncthreads();
  mx = fmaxf(fmaxf(red[0], red[1]), fmaxf(red[2], red[3]));
  float sm = 0.f;
  #pragma unroll
  for (int k = 0; k < 8; ++k) { float e = __expf(xc[k] - mx); xc[k] = e; sm += e; }
  sm = wred(sm);
  __syncthreads();
  if (lane == 0) red[wv] = sm;
  __syncthreads();
  float inv = 1.f / (red[0] + red[1] + red[2] + red[3]);
  #pragma unroll
  for (int k = 0; k < 8; ++k) ws[tid + k * 256] = xc[k] * inv;
  for (int l = tid; l < L; l += 256) { ms[l] = m[b * L + l]; rs[l] = r[b * L + l]; }
  __syncthreads();

  for (int j = 0; j < 4; ++j) {
    int d = dt + wv * 4 + j;
    const float* row = v + ((size_t)b * D + d) * L;
    float a1 = 0.f, a2 = 0.f;
    #pragma unroll
    for (int k2 = 0; k2 < 8; ++k2) {
      int l = lane * 4 + k2 * 256;
      float4_ x4 = *(const float4_*)&row[l];
      #pragma unroll
      for (int i = 0; i < 4; ++i) {
        float u = (x4[i] - ms[l + i]) * rs[l + i];
        float w = ws[l + i];
        a1 += w * u; a2 += w * u * u;
      }
    }
    a1 = wred(a1); a2 = wred(a2);
    if (lane == 0) { A1[b * D + d] = a1; A2[b * D + d] = a2; }
  }
}

// ---- per-b: att_mean/std -> skip (this layer) + fcq ----
__global__ void k_skip(const float* __restrict__ A1, const float* __restrict__ A2,
                       const float* __restrict__ g, const float* __restrict__ be,
                       const float* __restrict__ fcw, const float* __restrict__ fcb,
                       const float* __restrict__ fcqw,
                       float* __restrict__ skip_i, float* __restrict__ fcq) {
  __shared__ float am[D], as_[D];
  int b = blockIdx.x, t = threadIdx.x;
  {
    float a1 = A1[b * D + t], a2 = A2[b * D + t], gg = g[t];
    am[t] = gg * a1 + be[t];
    float var = gg * gg * (a2 - a1 * a1);
    as_[t] = sqrtf(fmaxf(var, EPS_STAT));
  }
  __syncthreads();
  float s = fcb[t], fq = 0.f;
  const float* wr = fcw + t * 2 * D;
  const float* qr = fcqw + t * D;
  for (int d = 0; d < D; ++d) {
    s += wr[d] * am[d] + wr[D + d] * as_[d];
    fq += qr[d] * am[d];
  }
  skip_i[b * D + t] = s;
  fcq[b * D + t] = fq;
}

// ---- fused FFN (layer 0) + layer-1 pass1 tail ----
// Round-6 measured-best GEMM structure, unchanged. Tail: after the epilogue
// barrier, re-read this block's dst tile (L2-hot) and run pass1-v2's exact
// body (same decomposition/reduction order -> bit-identical m/r/S1p/S2p),
// eliminating layer-1's k_pass1 launch and its full HBM read of v.
constexpr int MT = 64;

#define GEMM1_HALF(H0, ACC)                                                          \
  {                                                                                  \
    const unsigned short* wp0 = w1b + (size_t)((H0) + lr) * D + lq * 8;              \
    const unsigned short* wp1 = wp0 + 16 * D;                                        \
    short8 wr0[8], wr1[8];                                                           \
    _Pragma("unroll")                                                                \
    for (int kk = 0; kk < 8; ++kk) {                                                 \
      wr0[kk] = *(const short8*)(wp0 + kk * 32);                                     \
      wr1[kk] = *(const short8*)(wp1 + kk * 32);                                     \
    }                                                                                \
    int abase = lq * 512 + lr * 8;                                                   \
    _Pragma("unroll")                                                                \
    for (int kk = 0; kk < 8; ++kk) {                                                 \
      int nb = abase + kk * 2048;                                                    \
      short8 bf0 = *(const short8*)&us[nb];                                          \
      short8 bf1 = *(const short8*)&us[nb + 128];                                    \
      short8 bf2 = *(const short8*)&us[nb + 256];                                    \
      short8 bf3 = *(const short8*)&us[nb + 384];                                    \
      ACC[0][0] = __builtin_amdgcn_mfma_f32_16x16x32_bf16(wr0[kk], bf0, ACC[0][0],0,0,0);\
      ACC[0][1] = __builtin_amdgcn_mfma_f32_16x16x32_bf16(wr0[kk], bf1, ACC[0][1],0,0,0);\
      ACC[0][2] = __builtin_amdgcn_mfma_f32_16x16x32_bf16(wr0[kk], bf2, ACC[0][2],0,0,0);\
      ACC[0][3] = __builtin_amdgcn_mfma_f32_16x16x32_bf16(wr0[kk], bf3, ACC[0][3],0,0,0);\
      ACC[1][0] = __builtin_amdgcn_mfma_f32_16x16x32_bf16(wr1[kk], bf0, ACC[1][0],0,0,0);\
      ACC[1][1] = __builtin_amdgcn_mfma_f32_16x16x32_bf16(wr1[kk], bf1, ACC[1][1],0,0,0);\
      ACC[1][2] = __builtin_amdgcn_mfma_f32_16x16x32_bf16(wr1[kk], bf2, ACC[1][2],0,0,0);\
      ACC[1][3] = __builtin_amdgcn_mfma_f32_16x16x32_bf16(wr1[kk], bf3, ACC[1][3],0,0,0);\
    }                                                                                \
  }

#define H1_WRITE(H0, ACC)                                                            \
  {                                                                                  \
    _Pragma("unroll")                                                                \
    for (int mh = 0; mh < 2; ++mh) {                                                 \
      int hb = (H0) + mh * 16 + lq * 4;                                              \
      float b10 = b1[hb], b11 = b1[hb + 1], b12 = b1[hb + 2], b13 = b1[hb + 3];      \
      int grp = ((hb >> 3) + 32) & 63;                                               \
      int jh0 = hb & 7;                                                              \
      _Pragma("unroll")                                                              \
      for (int nt = 0; nt < 4; ++nt) {                                               \
        int tok = nt * 16 + lr;                                                      \
        uint2 pk;                                                                    \
        pk.x = pk2bf(fmaxf(ACC[mh][nt][0] + b10, 0.f),                               \
                     fmaxf(ACC[mh][nt][1] + b11, 0.f));                              \
        pk.y = pk2bf(fmaxf(ACC[mh][nt][2] + b12, 0.f),                               \
                     fmaxf(ACC[mh][nt][3] + b13, 0.f));                              \
        *(uint2*)&us[grp * 512 + tok * 8 + jh0] = pk;                                \
      }                                                                              \
    }                                                                                \
  }

#define GEMM2_HALF(M0, ACC2)                                                         \
  {                                                                                  \
    const unsigned short* wp = w2b + (size_t)((M0) + lr) * H + lq * 8;               \
    short8 wrg[16];                                                                  \
    _Pragma("unroll")                                                                \
    for (int kk = 0; kk < 16; ++kk) wrg[kk] = *(const short8*)(wp + kk * 32);        \
    _Pragma("unroll")                                                                \
    for (int kk = 0; kk < 16; ++kk) {                                                \
      int hb = ((kk * 4 + lq + 32) & 63) * 512 + lr * 8;                             \
      short8 hf0 = *(const short8*)&us[hb];                                          \
      short8 hf1 = *(const short8*)&us[hb + 128];                                    \
      short8 hf2 = *(const short8*)&us[hb + 256];                                    \
      short8 hf3 = *(const short8*)&us[hb + 384];                                    \
      ACC2[0] = __builtin_amdgcn_mfma_f32_16x16x32_bf16(wrg[kk], hf0, ACC2[0], 0, 0, 0);\
      ACC2[1] = __builtin_amdgcn_mfma_f32_16x16x32_bf16(wrg[kk], hf1, ACC2[1], 0, 0, 0);\
      ACC2[2] = __builtin_amdgcn_mfma_f32_16x16x32_bf16(wrg[kk], hf2, ACC2[2], 0, 0, 0);\
      ACC2[3] = __builtin_amdgcn_mfma_f32_16x16x32_bf16(wrg[kk], hf3, ACC2[3], 0, 0, 0);\
    }                                                                                \
  }

#define EPI_HALF(M0, ACC2)                                                           \
  {                                                                                  \
    _Pragma("unroll")                                                                \
    for (int i = 0; i < 4; ++i) {                                                    \
      int d = (M0) + lq * 4 + i;                                                     \
      float bb = b2_s[d] + fcq_s[d];                                                 \
      size_t rowoff = ((size_t)b * D + d) * L + l0;                                  \
      _Pragma("unroll")                                                              \
      for (int nt = 0; nt < 4; ++nt) {                                               \
        int tok = nt * 16 + lr;                                                      \
        dst[rowoff + tok] = ACC2[nt][i] + bb + src[rowoff + tok];                    \
      }                                                                              \
    }                                                                                \
  }

__global__ __launch_bounds__(512, 4) void k_ffn(
    const float* src, float* dst, const float* __restrict__ fcq,
    const unsigned short* __restrict__ w1b, const float* __restrict__ b1,
    const unsigned short* __restrict__ w2b, const float* __restrict__ b2,
    const float* __restrict__ g, const float* __restrict__ be,
    float* __restrict__ m_o, float* __restrict__ r_o,
    float* __restrict__ S1p, float* __restrict__ S2p) {
  __shared__ __align__(16) unsigned short us[32768];   // 64 KB
  __shared__ float fcq_s[D], g_s[D], be_s[D], b2_s[D];
  __shared__ __align__(16) float mu_s[MT], rs_s[MT];
  float* part1 = (float*)us;            // [32][64] floats = 8KB (dead before pack)
  float* part2 = (float*)(us + 4096);   // next 8KB

  int blk = blockIdx.x;
  int b = blk >> 5;
  int tile = blk & 31;
  int l0 = tile * MT;
  int tid = threadIdx.x;
  int lane4 = tid & 15, rg = tid >> 4;
  int wv = tid >> 6, lane = tid & 63, lr = lane & 15, lq = lane >> 4;

  if (tid < D) {
    fcq_s[tid] = fcq[b * D + tid];
    g_s[tid] = g[tid]; be_s[tid] = be[tid]; b2_s[tid] = b2[tid];
  }
  __syncthreads();

  // ---- stage 1: vectorized load (8x float4), add fcq, token LN stats ----
  const float* vrow = src + ((size_t)b * D + rg * 8) * L + l0 + lane4 * 4;
  {
    float4_ vv[8];
    float4_ s1 = {0.f, 0.f, 0.f, 0.f}, s2 = {0.f, 0.f, 0.f, 0.f};
    #pragma unroll
    for (int j = 0; j < 8; ++j) {
      float4_ x = *(const float4_*)&vrow[(size_t)j * L];
      x = x + fcq_s[rg * 8 + j];
      vv[j] = x; s1 += x; s2 += x * x;
    }
    *(float4_*)&part1[rg * 64 + lane4 * 4] = s1;
    *(float4_*)&part2[rg * 64 + lane4 * 4] = s2;
    __syncthreads();
    if (tid < MT) {
      float a = 0.f, c = 0.f;
      #pragma unroll
      for (int q = 0; q < 32; ++q) { a += part1[q * 64 + tid]; c += part2[q * 64 + tid]; }
      float mu = a * (1.f / D);
      float var = c * (1.f / D) - mu * mu;
      mu_s[tid] = mu; rs_s[tid] = rsqrtf(var + EPS_LN);
    }
    __syncthreads();
    float4_ mu4 = *(const float4_*)&mu_s[lane4 * 4];
    float4_ rs4 = *(const float4_*)&rs_s[lane4 * 4];
    #pragma unroll
    for (int c = 0; c < 4; ++c) {
      uint4 pw;
      unsigned* pp = &pw.x;
      #pragma unroll
      for (int jj = 0; jj < 4; ++jj) {
        int d0 = rg * 8 + jj * 2;
        pp[jj] = pk2bf((vv[jj * 2][c]     - mu4[c]) * rs4[c] * g_s[d0]     + be_s[d0],
                       (vv[jj * 2 + 1][c] - mu4[c]) * rs4[c] * g_s[d0 + 1] + be_s[d0 + 1]);
      }
      *(uint4*)&us[(rg * 64 + lane4 * 4 + c) * 8] = pw;
    }
  }
  __syncthreads();

  float4_ zero = {0.f, 0.f, 0.f, 0.f};

  {
    float4_ accA[2][4];
    #pragma unroll
    for (int i = 0; i < 2; ++i)
      #pragma unroll
      for (int j = 0; j < 4; ++j) accA[i][j] = zero;
    GEMM1_HALF(wv * 32, accA)
    H1_WRITE(wv * 32, accA)
  }
  {
    float4_ accB[2][4];
    #pragma unroll
    for (int i = 0; i < 2; ++i)
      #pragma unroll
      for (int j = 0; j < 4; ++j) accB[i][j] = zero;
    GEMM1_HALF(256 + wv * 32, accB)
    __syncthreads();               // all a_tile reads done (WAR)
    H1_WRITE(256 + wv * 32, accB)
  }
  __syncthreads();                 // h1 fully visible

  {
    float4_ acc2[4];
    #pragma unroll
    for (int j = 0; j < 4; ++j) acc2[j] = zero;
    GEMM2_HALF(wv * 16, acc2)
    EPI_HALF(wv * 16, acc2)
  }
  {
    float4_ acc2[4];
    #pragma unroll
    for (int j = 0; j < 4; ++j) acc2[j] = zero;
    GEMM2_HALF(128 + wv * 16, acc2)
    EPI_HALF(128 + wv * 16, acc2)
  }

  // ---- fused layer-1 pass1 tail: re-read this block's dst tile (L2-hot) ----
  // __syncthreads drains vmcnt -> all dst writes of this block complete/visible.
  __syncthreads();
  {
    const float* drow = dst + ((size_t)b * D + rg * 8) * L + l0 + lane4 * 4;
    float4_ vv[8];
    float4_ s1 = {0.f, 0.f, 0.f, 0.f}, s2 = {0.f, 0.f, 0.f, 0.f};
    #pragma unroll
    for (int j = 0; j < 8; ++j) {
      float4_ x = *(const float4_*)&drow[(size_t)j * L];
      vv[j] = x; s1 += x; s2 += x * x;
    }
    *(float4_*)&part1[rg * 64 + lane4 * 4] = s1;
    *(float4_*)&part2[rg * 64 + lane4 * 4] = s2;
    __syncthreads();
    if (tid < 64) {
      float a = 0.f, c = 0.f;
      #pragma unroll
      for (int q = 0; q < 32; ++q) { a += part1[q * 64 + tid]; c += part2[q * 64 + tid]; }
      float mu = a * (1.f / D);
      float var = c * (1.f / D) - mu * mu;
      float rsq = rsqrtf(var + EPS_LN);
      mu_s[tid] = mu; rs_s[tid] = rsq;
      m_o[b * L + l0 + tid] = mu;
      r_o[b * L + l0 + tid] = rsq;
    }
    __syncthreads();
    {
      float4_ mu4 = *(const float4_*)&mu_s[lane4 * 4];
      float4_ rs4 = *(const float4_*)&rs_s[lane4 * 4];
      size_t obase = ((size_t)b * 32 + tile) * D + rg * 8;
      #pragma unroll
      for (int j = 0; j < 8; ++j) {
        float4_ u = (vv[j] - mu4) * rs4;
        float a1 = u[0] + u[1] + u[2] + u[3];
        float a2 = u[0] * u[0] + u[1] * u[1] + u[2] * u[2] + u[3] * u[3];
        #pragma unroll
        for (int o = 1; o < 16; o <<= 1) {
          a1 += __shfl_xor(a1, o, 64);
          a2 += __shfl_xor(a2, o, 64);
        }
        if (lane4 == 0) { S1p[obase + j] = a1; S2p[obase + j] = a2; }
      }
    }
  }
}

// ---- final: y = relu(skip0+skip1); batchnorm over B per channel d ----
__global__ void k_bn(const float* __restrict__ s0, const float* __restrict__ s1,
                     float* __restrict__ out) {
  int d = threadIdx.x;
  float s = 0.f, q = 0.f;
  for (int b = 0; b < B; ++b) {
    float y = fmaxf(s0[b * D + d] + s1[b * D + d], 0.f);
    s += y; q += y * y;
  }
  float mu = s * (1.f / B);
  float var = q * (1.f / B) - mu * mu;
  float rs = rsqrtf(var + EPS_BN);
  for (int b = 0; b < B; ++b) {
    float y = fmaxf(s0[b * D + d] + s1[b * D + d], 0.f);
    out[b * D + d] = (y - mu) * rs;
  }
}

extern "C" void kernel_launch(void* const* d_in, const int* in_sizes, int n_in,
                              void* d_out, int out_size, void* d_ws, size_t ws_size,
                              hipStream_t stream) {
  const float* x    = (const float*)d_in[0];
  const float* wk   = (const float*)d_in[1];
  const float* wq   = (const float*)d_in[2];
  const float* fcqw = (const float*)d_in[3];
  const float* fcw  = (const float*)d_in[4];
  const float* fcb  = (const float*)d_in[5];
  const float* ag   = (const float*)d_in[6];
  const float* abt  = (const float*)d_in[7];
  const float* w1   = (const float*)d_in[8];
  const float* b1   = (const float*)d_in[9];
  const float* w2   = (const float*)d_in[10];
  const float* b2   = (const float*)d_in[11];
  const float* fg   = (const float*)d_in[12];
  const float* fb   = (const float*)d_in[13];
  float* out = (float*)d_out;

  char* p = (char*)d_ws;
  float* v_ws = (float*)p;  p += (size_t)B * D * L * 4;
  float* m    = (float*)p;  p += (size_t)B * L * 4;
  float* r    = (float*)p;  p += (size_t)B * L * 4;
  float* sc   = (float*)p;  p += (size_t)B * L * 4;
  float* S1p  = (float*)p;  p += (size_t)B * 32 * D * 4;
  float* S2p  = (float*)p;  p += (size_t)B * 32 * D * 4;
  float* gw   = (float*)p;  p += (size_t)B * D * 4;
  float* A1   = (float*)p;  p += (size_t)B * D * 4;
  float* A2   = (float*)p;  p += (size_t)B * D * 4;
  float* fcqv = (float*)p;  p += (size_t)B * D * 4;
  float* sk0  = (float*)p;  p += (size_t)B * D * 4;
  float* sk1  = (float*)p;  p += (size_t)B * D * 4;
  float* Gg   = (float*)p;  p += (size_t)B * 4;
  unsigned short* w1b = (unsigned short*)p; p += (size_t)H * D * 2;
  unsigned short* w2b = (unsigned short*)p; p += (size_t)D * H * 2;

  // layer-1 FFN weights never needed (its output v is dead in the reference)
  k_convw<<<256, 256, 0, stream>>>(w1, w2, w1b, w2b);

  // ---- layer 0 ----
  k_pass1<<<B * 32, 512, 0, stream>>>(x, m, r, S1p, S2p);
  k_qproj<<<B, 256, 0, stream>>>(S1p, S2p, ag, abt, wq, wk, gw, Gg);
  k_scores<<<B * 8, 512, 0, stream>>>(x, m, r, gw, Gg, sc);
  k_redw<<<B * 16, 256, 0, stream>>>(x, m, r, sc, A1, A2);
  k_skip<<<B, 256, 0, stream>>>(A1, A2, ag, abt, fcw, fcb, fcqw, sk0, fcqv);
  // FFN (layer 0 only) + fused layer-1 pass1 (writes m, r, S1p, S2p for i=1)
  k_ffn<<<B * (L / MT), 512, 0, stream>>>(x, v_ws, fcqv, w1b, b1, w2b, b2,
                                          fg, fb, m, r, S1p, S2p);

  // ---- layer 1 (pass1 already fused into k_ffn's tail) ----
  k_qproj<<<B, 256, 0, stream>>>(S1p, S2p, ag + D, abt + D,
                                 wq + (size_t)KP * 2 * D, wk + (size_t)KP * D,
                                 gw, Gg);
  k_scores<<<B * 8, 512, 0, stream>>>(v_ws, m, r, gw, Gg, sc);
  k_redw<<<B * 16, 256, 0, stream>>>(v_ws, m, r, sc, A1, A2);
  k_skip<<<B, 256, 0, stream>>>(A1, A2, ag + D, abt + D,
                                fcw + (size_t)D * 2 * D, fcb + D,
                                fcqw + (size_t)D * D, sk1, fcqv);

  k_bn<<<1, 256, 0, stream>>>(sk0, sk1, out);
}

// Round 12
// 555.196 us; speedup vs baseline: 1.4497x; 1.0776x over previous
//
#include <hip/hip_runtime.h>
#include <hip/hip_bf16.h>

#define DEV __device__ __forceinline__

constexpr int B = 64, D = 256, L = 2048, H = 512, KP = 128;
constexpr float EPS_LN = 1e-6f, EPS_STAT = 1e-10f, EPS_BN = 1e-5f;
constexpr float SCALE = 0.088388347648318447f; // 1/sqrt(128)

typedef __attribute__((ext_vector_type(8))) short short8;
typedef __attribute__((ext_vector_type(4))) float float4_;

DEV unsigned short f2bf(float x) {
  unsigned u = __builtin_bit_cast(unsigned, x);
  u += 0x7fffu + ((u >> 16) & 1u);           // RNE
  return (unsigned short)(u >> 16);
}

DEV unsigned pk2bf(float a, float b) {       // two RNE cvts packed into a dword
  return (unsigned)f2bf(a) | ((unsigned)f2bf(b) << 16);
}

DEV float bflo(unsigned pk) { return __builtin_bit_cast(float, pk << 16); }
DEV float bfhi(unsigned pk) { return __builtin_bit_cast(float, pk & 0xffff0000u); }

DEV float wred(float x) {
  #pragma unroll
  for (int o = 32; o > 0; o >>= 1) x += __shfl_down(x, o, 64);
  return x;
}
DEV float wredmax(float x) {
  #pragma unroll
  for (int o = 32; o > 0; o >>= 1) x = fmaxf(x, __shfl_down(x, o, 64));
  return x;
}

// ---- convert w1/w2 (layer 0 only; layer-1 FFN is dead code) ----
__global__ void k_convw(const float* __restrict__ w1, const float* __restrict__ w2,
                        unsigned short* __restrict__ w1b, unsigned short* __restrict__ w2b) {
  int n = H * D;
  for (int i = blockIdx.x * blockDim.x + threadIdx.x; i < n; i += gridDim.x * blockDim.x) {
    w1b[i] = f2bf(w1[i]);
    w2b[i] = f2bf(w2[i]);
  }
}

// ---- P1 v2 (layer 0 only, fp32 x): token-LN stats + per-(b,d,tile) sums ----
__global__ __launch_bounds__(512, 4) void k_pass1(
    const float* __restrict__ v, float* __restrict__ m, float* __restrict__ r,
    float* __restrict__ S1p, float* __restrict__ S2p) {
  __shared__ float part1[32 * 64], part2[32 * 64];   // 16 KB
  __shared__ __align__(16) float mu_s[64], rs_s[64];

  int blk = blockIdx.x;
  int b = blk >> 5, tile = blk & 31, l0 = tile * 64;
  int tid = threadIdx.x;
  int lane4 = tid & 15, rg = tid >> 4;      // rg 0..31: 8 d-rows; lane4: 4 tokens

  const float* vrow = v + ((size_t)b * D + rg * 8) * L + l0 + lane4 * 4;
  float4_ vv[8];
  float4_ s1 = {0.f, 0.f, 0.f, 0.f}, s2 = {0.f, 0.f, 0.f, 0.f};
  #pragma unroll
  for (int j = 0; j < 8; ++j) {
    float4_ x = *(const float4_*)&vrow[(size_t)j * L];
    vv[j] = x; s1 += x; s2 += x * x;
  }
  *(float4_*)&part1[rg * 64 + lane4 * 4] = s1;
  *(float4_*)&part2[rg * 64 + lane4 * 4] = s2;
  __syncthreads();
  if (tid < 64) {
    float a = 0.f, c = 0.f;
    #pragma unroll
    for (int q = 0; q < 32; ++q) { a += part1[q * 64 + tid]; c += part2[q * 64 + tid]; }
    float mu = a * (1.f / D);
    float var = c * (1.f / D) - mu * mu;
    float rsq = rsqrtf(var + EPS_LN);
    mu_s[tid] = mu; rs_s[tid] = rsq;
    m[b * L + l0 + tid] = mu;
    r[b * L + l0 + tid] = rsq;
  }
  __syncthreads();
  {
    float4_ mu4 = *(const float4_*)&mu_s[lane4 * 4];
    float4_ rs4 = *(const float4_*)&rs_s[lane4 * 4];
    size_t obase = ((size_t)b * 32 + tile) * D + rg * 8;
    #pragma unroll
    for (int j = 0; j < 8; ++j) {
      float4_ u = (vv[j] - mu4) * rs4;
      float a1 = u[0] + u[1] + u[2] + u[3];
      float a2 = u[0] * u[0] + u[1] * u[1] + u[2] * u[2] + u[3] * u[3];
      #pragma unroll
      for (int o = 1; o < 16; o <<= 1) {
        a1 += __shfl_xor(a1, o, 64);
        a2 += __shfl_xor(a2, o, 64);
      }
      if (lane4 == 0) { S1p[obase + j] = a1; S2p[obase + j] = a2; }
    }
  }
}

// ---- per-b: reduce partials -> mu/sd over L -> q -> gw (+ G = sum_d gw) ----
__global__ void k_qproj(const float* __restrict__ S1p, const float* __restrict__ S2p,
                        const float* __restrict__ g, const float* __restrict__ be,
                        const float* __restrict__ wq, const float* __restrict__ wk,
                        float* __restrict__ gw, float* __restrict__ Gg) {
  __shared__ float cat[2 * D];
  __shared__ float qs[KP];
  __shared__ float gsum[4];
  int b = blockIdx.x, t = threadIdx.x;  // 256 threads
  {
    float s1 = 0.f, s2 = 0.f;
    for (int k = 0; k < 32; ++k) {
      s1 += S1p[((size_t)b * 32 + k) * D + t];
      s2 += S2p[((size_t)b * 32 + k) * D + t];
    }
    s1 *= (1.f / L); s2 *= (1.f / L);
    float gg = g[t];
    cat[t] = gg * s1 + be[t];
    float var = gg * gg * (s2 - s1 * s1);
    cat[D + t] = sqrtf(fmaxf(var, EPS_STAT));
  }
  __syncthreads();
  if (t < KP) {
    float s = 0.f;
    const float* wr = wq + t * 2 * D;
    for (int e = 0; e < 2 * D; ++e) s += cat[e] * wr[e];
    qs[t] = s;
  }
  __syncthreads();
  {
    float s = 0.f;
    for (int k = 0; k < KP; ++k) s += wk[k * D + t] * qs[k];
    float gwv = g[t] * SCALE * s;  // beta const dropped (softmax-invariant)
    gw[b * D + t] = gwv;
    float gs = wred(gwv);
    if ((t & 63) == 0) gsum[t >> 6] = gs;
  }
  __syncthreads();
  if (t == 0) Gg[b] = gsum[0] + gsum[1] + gsum[2] + gsum[3];
}

// ---- scores (layer 0, fp32 x): sc = r*(sum_d v*g - m*G) ----
__global__ __launch_bounds__(512) void k_scores(
    const float* __restrict__ v, const float* __restrict__ m,
    const float* __restrict__ r, const float* __restrict__ gw,
    const float* __restrict__ Gg, float* __restrict__ sc) {
  __shared__ float gws[D];
  __shared__ float sh[256];
  int blk = blockIdx.x;
  int b = blk >> 3, l0 = (blk & 7) * 256;
  int tid = threadIdx.x, lt = tid & 255, dh = tid >> 8;
  if (tid < D) gws[tid] = gw[b * D + tid];
  __syncthreads();
  int l = l0 + lt;
  const float* p = v + ((size_t)b * D + dh * 128) * L + l;
  float s = 0.f;
  #pragma unroll 8
  for (int d = 0; d < 128; ++d) s += p[(size_t)d * L] * gws[dh * 128 + d];
  if (dh == 1) sh[lt] = s;
  __syncthreads();
  if (dh == 0) {
    float tot = s + sh[lt];
    sc[b * L + l] = r[b * L + l] * (tot - m[b * L + l] * Gg[b]);
  }
}

// ---- scores (layer 1, bf16 v): ushort2 loads, 2 tokens/lane ----
__global__ __launch_bounds__(512) void k_scores_bf(
    const unsigned short* __restrict__ v, const float* __restrict__ m,
    const float* __restrict__ r, const float* __restrict__ gw,
    const float* __restrict__ Gg, float* __restrict__ sc) {
  __shared__ float gws[D];
  __shared__ float sh0[256], sh1[256];
  int blk = blockIdx.x;
  int b = blk >> 2, l0 = (blk & 3) * 512;
  int tid = threadIdx.x, lt = tid & 255, dh = tid >> 8;
  if (tid < D) gws[tid] = gw[b * D + tid];
  __syncthreads();
  int l = l0 + lt * 2;
  const unsigned short* p = v + ((size_t)b * D + dh * 128) * L + l;
  float s0 = 0.f, s1 = 0.f;
  #pragma unroll 8
  for (int d = 0; d < 128; ++d) {
    unsigned pk = *(const unsigned*)&p[(size_t)d * L];
    float g = gws[dh * 128 + d];
    s0 += bflo(pk) * g;
    s1 += bfhi(pk) * g;
  }
  if (dh == 1) { sh0[lt] = s0; sh1[lt] = s1; }
  __syncthreads();
  if (dh == 0) {
    float G = Gg[b];
    float t0 = s0 + sh0[lt], t1 = s1 + sh1[lt];
    float2 o;
    o.x = r[b * L + l]     * (t0 - m[b * L + l]     * G);
    o.y = r[b * L + l + 1] * (t1 - m[b * L + l + 1] * G);
    *(float2*)&sc[b * L + l] = o;
  }
}

// ---- redw (layer 0, fp32): softmax recompute + weighted stats ----
__global__ __launch_bounds__(256) void k_redw(
    const float* __restrict__ v, const float* __restrict__ m, const float* __restrict__ r,
    const float* __restrict__ sc, float* __restrict__ A1, float* __restrict__ A2) {
  __shared__ float ws[L];
  __shared__ float ms[L], rs[L];
  __shared__ float red[4];
  int blk = blockIdx.x;
  int b = blk >> 4, dt = (blk & 15) * 16;
  int tid = threadIdx.x, wv = tid >> 6, lane = tid & 63;

  float xc[8];
  float mx = -1e30f;
  #pragma unroll
  for (int k = 0; k < 8; ++k) {
    float x = sc[b * L + tid + k * 256];
    xc[k] = x; mx = fmaxf(mx, x);
  }
  mx = wredmax(mx);
  if (lane == 0) red[wv] = mx;
  __syncthreads();
  mx = fmaxf(fmaxf(red[0], red[1]), fmaxf(red[2], red[3]));
  float sm = 0.f;
  #pragma unroll
  for (int k = 0; k < 8; ++k) { float e = __expf(xc[k] - mx); xc[k] = e; sm += e; }
  sm = wred(sm);
  __syncthreads();
  if (lane == 0) red[wv] = sm;
  __syncthreads();
  float inv = 1.f / (red[0] + red[1] + red[2] + red[3]);
  #pragma unroll
  for (int k = 0; k < 8; ++k) ws[tid + k * 256] = xc[k] * inv;
  for (int l = tid; l < L; l += 256) { ms[l] = m[b * L + l]; rs[l] = r[b * L + l]; }
  __syncthreads();

  for (int j = 0; j < 4; ++j) {
    int d = dt + wv * 4 + j;
    const float* row = v + ((size_t)b * D + d) * L;
    float a1 = 0.f, a2 = 0.f;
    #pragma unroll
    for (int k2 = 0; k2 < 8; ++k2) {
      int l = lane * 4 + k2 * 256;
      float4_ x4 = *(const float4_*)&row[l];
      #pragma unroll
      for (int i = 0; i < 4; ++i) {
        float u = (x4[i] - ms[l + i]) * rs[l + i];
        float w = ws[l + i];
        a1 += w * u; a2 += w * u * u;
      }
    }
    a1 = wred(a1); a2 = wred(a2);
    if (lane == 0) { A1[b * D + d] = a1; A2[b * D + d] = a2; }
  }
}

// ---- redw (layer 1, bf16 v) ----
__global__ __launch_bounds__(256) void k_redw_bf(
    const unsigned short* __restrict__ v, const float* __restrict__ m,
    const float* __restrict__ r, const float* __restrict__ sc,
    float* __restrict__ A1, float* __restrict__ A2) {
  __shared__ float ws[L];
  __shared__ float ms[L], rs[L];
  __shared__ float red[4];
  int blk = blockIdx.x;
  int b = blk >> 4, dt = (blk & 15) * 16;
  int tid = threadIdx.x, wv = tid >> 6, lane = tid & 63;

  float xc[8];
  float mx = -1e30f;
  #pragma unroll
  for (int k = 0; k < 8; ++k) {
    float x = sc[b * L + tid + k * 256];
    xc[k] = x; mx = fmaxf(mx, x);
  }
  mx = wredmax(mx);
  if (lane == 0) red[wv] = mx;
  __syncthreads();
  mx = fmaxf(fmaxf(red[0], red[1]), fmaxf(red[2], red[3]));
  float sm = 0.f;
  #pragma unroll
  for (int k = 0; k < 8; ++k) { float e = __expf(xc[k] - mx); xc[k] = e; sm += e; }
  sm = wred(sm);
  __syncthreads();
  if (lane == 0) red[wv] = sm;
  __syncthreads();
  float inv = 1.f / (red[0] + red[1] + red[2] + red[3]);
  #pragma unroll
  for (int k = 0; k < 8; ++k) ws[tid + k * 256] = xc[k] * inv;
  for (int l = tid; l < L; l += 256) { ms[l] = m[b * L + l]; rs[l] = r[b * L + l]; }
  __syncthreads();

  for (int j = 0; j < 4; ++j) {
    int d = dt + wv * 4 + j;
    const unsigned short* row = v + ((size_t)b * D + d) * L;
    float a1 = 0.f, a2 = 0.f;
    #pragma unroll
    for (int k2 = 0; k2 < 8; ++k2) {
      int l = lane * 4 + k2 * 256;
      uint2 pk = *(const uint2*)&row[l];
      float x4[4] = { bflo(pk.x), bfhi(pk.x), bflo(pk.y), bfhi(pk.y) };
      #pragma unroll
      for (int i = 0; i < 4; ++i) {
        float u = (x4[i] - ms[l + i]) * rs[l + i];
        float w = ws[l + i];
        a1 += w * u; a2 += w * u * u;
      }
    }
    a1 = wred(a1); a2 = wred(a2);
    if (lane == 0) { A1[b * D + d] = a1; A2[b * D + d] = a2; }
  }
}

// ---- per-b: att_mean/std -> skip (this layer) + fcq ----
__global__ void k_skip(const float* __restrict__ A1, const float* __restrict__ A2,
                       const float* __restrict__ g, const float* __restrict__ be,
                       const float* __restrict__ fcw, const float* __restrict__ fcb,
                       const float* __restrict__ fcqw,
                       float* __restrict__ skip_i, float* __restrict__ fcq) {
  __shared__ float am[D], as_[D];
  int b = blockIdx.x, t = threadIdx.x;
  {
    float a1 = A1[b * D + t], a2 = A2[b * D + t], gg = g[t];
    am[t] = gg * a1 + be[t];
    float var = gg * gg * (a2 - a1 * a1);
    as_[t] = sqrtf(fmaxf(var, EPS_STAT));
  }
  __syncthreads();
  float s = fcb[t], fq = 0.f;
  const float* wr = fcw + t * 2 * D;
  const float* qr = fcqw + t * D;
  for (int d = 0; d < D; ++d) {
    s += wr[d] * am[d] + wr[D + d] * as_[d];
    fq += qr[d] * am[d];
  }
  skip_i[b * D + t] = s;
  fcq[b * D + t] = fq;
}

// ---- fused FFN (layer 0) + bf16 v1 write + layer-1 pass1 tail ----
// dst is bf16: halves v1 write, tail re-read, and layer-1 scores/redw reads.
// Tail stats computed FROM the rounded values (consistent with consumers).
constexpr int MT = 64;

#define GEMM1_HALF(H0, ACC)                                                          \
  {                                                                                  \
    const unsigned short* wp0 = w1b + (size_t)((H0) + lr) * D + lq * 8;              \
    const unsigned short* wp1 = wp0 + 16 * D;                                        \
    short8 wr0[8], wr1[8];                                                           \
    _Pragma("unroll")                                                                \
    for (int kk = 0; kk < 8; ++kk) {                                                 \
      wr0[kk] = *(const short8*)(wp0 + kk * 32);                                     \
      wr1[kk] = *(const short8*)(wp1 + kk * 32);                                     \
    }                                                                                \
    int abase = lq * 512 + lr * 8;                                                   \
    _Pragma("unroll")                                                                \
    for (int kk = 0; kk < 8; ++kk) {                                                 \
      int nb = abase + kk * 2048;                                                    \
      short8 bf0 = *(const short8*)&us[nb];                                          \
      short8 bf1 = *(const short8*)&us[nb + 128];                                    \
      short8 bf2 = *(const short8*)&us[nb + 256];                                    \
      short8 bf3 = *(const short8*)&us[nb + 384];                                    \
      ACC[0][0] = __builtin_amdgcn_mfma_f32_16x16x32_bf16(wr0[kk], bf0, ACC[0][0],0,0,0);\
      ACC[0][1] = __builtin_amdgcn_mfma_f32_16x16x32_bf16(wr0[kk], bf1, ACC[0][1],0,0,0);\
      ACC[0][2] = __builtin_amdgcn_mfma_f32_16x16x32_bf16(wr0[kk], bf2, ACC[0][2],0,0,0);\
      ACC[0][3] = __builtin_amdgcn_mfma_f32_16x16x32_bf16(wr0[kk], bf3, ACC[0][3],0,0,0);\
      ACC[1][0] = __builtin_amdgcn_mfma_f32_16x16x32_bf16(wr1[kk], bf0, ACC[1][0],0,0,0);\
      ACC[1][1] = __builtin_amdgcn_mfma_f32_16x16x32_bf16(wr1[kk], bf1, ACC[1][1],0,0,0);\
      ACC[1][2] = __builtin_amdgcn_mfma_f32_16x16x32_bf16(wr1[kk], bf2, ACC[1][2],0,0,0);\
      ACC[1][3] = __builtin_amdgcn_mfma_f32_16x16x32_bf16(wr1[kk], bf3, ACC[1][3],0,0,0);\
    }                                                                                \
  }

#define H1_WRITE(H0, ACC)                                                            \
  {                                                                                  \
    _Pragma("unroll")                                                                \
    for (int mh = 0; mh < 2; ++mh) {                                                 \
      int hb = (H0) + mh * 16 + lq * 4;                                              \
      float b10 = b1[hb], b11 = b1[hb + 1], b12 = b1[hb + 2], b13 = b1[hb + 3];      \
      int grp = ((hb >> 3) + 32) & 63;                                               \
      int jh0 = hb & 7;                                                              \
      _Pragma("unroll")                                                              \
      for (int nt = 0; nt < 4; ++nt) {                                               \
        int tok = nt * 16 + lr;                                                      \
        uint2 pk;                                                                    \
        pk.x = pk2bf(fmaxf(ACC[mh][nt][0] + b10, 0.f),                               \
                     fmaxf(ACC[mh][nt][1] + b11, 0.f));                              \
        pk.y = pk2bf(fmaxf(ACC[mh][nt][2] + b12, 0.f),                               \
                     fmaxf(ACC[mh][nt][3] + b13, 0.f));                              \
        *(uint2*)&us[grp * 512 + tok * 8 + jh0] = pk;                                \
      }                                                                              \
    }                                                                                \
  }

#define GEMM2_HALF(M0, ACC2)                                                         \
  {                                                                                  \
    const unsigned short* wp = w2b + (size_t)((M0) + lr) * H + lq * 8;               \
    short8 wrg[16];                                                                  \
    _Pragma("unroll")                                                                \
    for (int kk = 0; kk < 16; ++kk) wrg[kk] = *(const short8*)(wp + kk * 32);        \
    _Pragma("unroll")                                                                \
    for (int kk = 0; kk < 16; ++kk) {                                                \
      int hb = ((kk * 4 + lq + 32) & 63) * 512 + lr * 8;                             \
      short8 hf0 = *(const short8*)&us[hb];                                          \
      short8 hf1 = *(const short8*)&us[hb + 128];                                    \
      short8 hf2 = *(const short8*)&us[hb + 256];                                    \
      short8 hf3 = *(const short8*)&us[hb + 384];                                    \
      ACC2[0] = __builtin_amdgcn_mfma_f32_16x16x32_bf16(wrg[kk], hf0, ACC2[0], 0, 0, 0);\
      ACC2[1] = __builtin_amdgcn_mfma_f32_16x16x32_bf16(wrg[kk], hf1, ACC2[1], 0, 0, 0);\
      ACC2[2] = __builtin_amdgcn_mfma_f32_16x16x32_bf16(wrg[kk], hf2, ACC2[2], 0, 0, 0);\
      ACC2[3] = __builtin_amdgcn_mfma_f32_16x16x32_bf16(wrg[kk], hf3, ACC2[3], 0, 0, 0);\
    }                                                                                \
  }

#define EPI_HALF(M0, ACC2)                                                           \
  {                                                                                  \
    _Pragma("unroll")                                                                \
    for (int i = 0; i < 4; ++i) {                                                    \
      int d = (M0) + lq * 4 + i;                                                     \
      float bb = b2_s[d] + fcq_s[d];                                                 \
      size_t rowoff = ((size_t)b * D + d) * L + l0;                                  \
      _Pragma("unroll")                                                              \
      for (int nt = 0; nt < 4; ++nt) {                                               \
        int tok = nt * 16 + lr;                                                      \
        dst[rowoff + tok] = f2bf(ACC2[nt][i] + bb + src[rowoff + tok]);              \
      }                                                                              \
    }                                                                                \
  }

__global__ __launch_bounds__(512, 4) void k_ffn(
    const float* src, unsigned short* dst, const float* __restrict__ fcq,
    const unsigned short* __restrict__ w1b, const float* __restrict__ b1,
    const unsigned short* __restrict__ w2b, const float* __restrict__ b2,
    const float* __restrict__ g, const float* __restrict__ be,
    float* __restrict__ m_o, float* __restrict__ r_o,
    float* __restrict__ S1p, float* __restrict__ S2p) {
  __shared__ __align__(16) unsigned short us[32768];   // 64 KB
  __shared__ float fcq_s[D], g_s[D], be_s[D], b2_s[D];
  __shared__ __align__(16) float mu_s[MT], rs_s[MT];
  float* part1 = (float*)us;            // [32][64] floats = 8KB (dead before pack)
  float* part2 = (float*)(us + 4096);   // next 8KB

  int blk = blockIdx.x;
  int b = blk >> 5;
  int tile = blk & 31;
  int l0 = tile * MT;
  int tid = threadIdx.x;
  int lane4 = tid & 15, rg = tid >> 4;
  int wv = tid >> 6, lane = tid & 63, lr = lane & 15, lq = lane >> 4;

  if (tid < D) {
    fcq_s[tid] = fcq[b * D + tid];
    g_s[tid] = g[tid]; be_s[tid] = be[tid]; b2_s[tid] = b2[tid];
  }
  __syncthreads();

  // ---- stage 1: vectorized load (8x float4), add fcq, token LN stats ----
  const float* vrow = src + ((size_t)b * D + rg * 8) * L + l0 + lane4 * 4;
  {
    float4_ vv[8];
    float4_ s1 = {0.f, 0.f, 0.f, 0.f}, s2 = {0.f, 0.f, 0.f, 0.f};
    #pragma unroll
    for (int j = 0; j < 8; ++j) {
      float4_ x = *(const float4_*)&vrow[(size_t)j * L];
      x = x + fcq_s[rg * 8 + j];
      vv[j] = x; s1 += x; s2 += x * x;
    }
    *(float4_*)&part1[rg * 64 + lane4 * 4] = s1;
    *(float4_*)&part2[rg * 64 + lane4 * 4] = s2;
    __syncthreads();
    if (tid < MT) {
      float a = 0.f, c = 0.f;
      #pragma unroll
      for (int q = 0; q < 32; ++q) { a += part1[q * 64 + tid]; c += part2[q * 64 + tid]; }
      float mu = a * (1.f / D);
      float var = c * (1.f / D) - mu * mu;
      mu_s[tid] = mu; rs_s[tid] = rsqrtf(var + EPS_LN);
    }
    __syncthreads();
    float4_ mu4 = *(const float4_*)&mu_s[lane4 * 4];
    float4_ rs4 = *(const float4_*)&rs_s[lane4 * 4];
    #pragma unroll
    for (int c = 0; c < 4; ++c) {
      uint4 pw;
      unsigned* pp = &pw.x;
      #pragma unroll
      for (int jj = 0; jj < 4; ++jj) {
        int d0 = rg * 8 + jj * 2;
        pp[jj] = pk2bf((vv[jj * 2][c]     - mu4[c]) * rs4[c] * g_s[d0]     + be_s[d0],
                       (vv[jj * 2 + 1][c] - mu4[c]) * rs4[c] * g_s[d0 + 1] + be_s[d0 + 1]);
      }
      *(uint4*)&us[(rg * 64 + lane4 * 4 + c) * 8] = pw;
    }
  }
  __syncthreads();

  float4_ zero = {0.f, 0.f, 0.f, 0.f};

  {
    float4_ accA[2][4];
    #pragma unroll
    for (int i = 0; i < 2; ++i)
      #pragma unroll
      for (int j = 0; j < 4; ++j) accA[i][j] = zero;
    GEMM1_HALF(wv * 32, accA)
    H1_WRITE(wv * 32, accA)
  }
  {
    float4_ accB[2][4];
    #pragma unroll
    for (int i = 0; i < 2; ++i)
      #pragma unroll
      for (int j = 0; j < 4; ++j) accB[i][j] = zero;
    GEMM1_HALF(256 + wv * 32, accB)
    __syncthreads();               // all a_tile reads done (WAR)
    H1_WRITE(256 + wv * 32, accB)
  }
  __syncthreads();                 // h1 fully visible

  {
    float4_ acc2[4];
    #pragma unroll
    for (int j = 0; j < 4; ++j) acc2[j] = zero;
    GEMM2_HALF(wv * 16, acc2)
    EPI_HALF(wv * 16, acc2)
  }
  {
    float4_ acc2[4];
    #pragma unroll
    for (int j = 0; j < 4; ++j) acc2[j] = zero;
    GEMM2_HALF(128 + wv * 16, acc2)
    EPI_HALF(128 + wv * 16, acc2)
  }

  // ---- fused layer-1 pass1 tail: re-read this block's bf16 dst tile ----
  // __syncthreads drains vmcnt -> all dst writes of this block visible.
  __syncthreads();
  {
    const unsigned short* drow = dst + ((size_t)b * D + rg * 8) * L + l0 + lane4 * 4;
    float4_ vv[8];
    float4_ s1 = {0.f, 0.f, 0.f, 0.f}, s2 = {0.f, 0.f, 0.f, 0.f};
    #pragma unroll
    for (int j = 0; j < 8; ++j) {
      uint2 pk = *(const uint2*)&drow[(size_t)j * L];
      float4_ x = { bflo(pk.x), bfhi(pk.x), bflo(pk.y), bfhi(pk.y) };
      vv[j] = x; s1 += x; s2 += x * x;
    }
    *(float4_*)&part1[rg * 64 + lane4 * 4] = s1;
    *(float4_*)&part2[rg * 64 + lane4 * 4] = s2;
    __syncthreads();
    if (tid < 64) {
      float a = 0.f, c = 0.f;
      #pragma unroll
      for (int q = 0; q < 32; ++q) { a += part1[q * 64 + tid]; c += part2[q * 64 + tid]; }
      float mu = a * (1.f / D);
      float var = c * (1.f / D) - mu * mu;
      float rsq = rsqrtf(var + EPS_LN);
      mu_s[tid] = mu; rs_s[tid] = rsq;
      m_o[b * L + l0 + tid] = mu;
      r_o[b * L + l0 + tid] = rsq;
    }
    __syncthreads();
    {
      float4_ mu4 = *(const float4_*)&mu_s[lane4 * 4];
      float4_ rs4 = *(const float4_*)&rs_s[lane4 * 4];
      size_t obase = ((size_t)b * 32 + tile) * D + rg * 8;
      #pragma unroll
      for (int j = 0; j < 8; ++j) {
        float4_ u = (vv[j] - mu4) * rs4;
        float a1 = u[0] + u[1] + u[2] + u[3];
        float a2 = u[0] * u[0] + u[1] * u[1] + u[2] * u[2] + u[3] * u[3];
        #pragma unroll
        for (int o = 1; o < 16; o <<= 1) {
          a1 += __shfl_xor(a1, o, 64);
          a2 += __shfl_xor(a2, o, 64);
        }
        if (lane4 == 0) { S1p[obase + j] = a1; S2p[obase + j] = a2; }
      }
    }
  }
}

// ---- final: y = relu(skip0+skip1); batchnorm over B per channel d ----
__global__ void k_bn(const float* __restrict__ s0, const float* __restrict__ s1,
                     float* __restrict__ out) {
  int d = threadIdx.x;
  float s = 0.f, q = 0.f;
  for (int b = 0; b < B; ++b) {
    float y = fmaxf(s0[b * D + d] + s1[b * D + d], 0.f);
    s += y; q += y * y;
  }
  float mu = s * (1.f / B);
  float var = q * (1.f / B) - mu * mu;
  float rs = rsqrtf(var + EPS_BN);
  for (int b = 0; b < B; ++b) {
    float y = fmaxf(s0[b * D + d] + s1[b * D + d], 0.f);
    out[b * D + d] = (y - mu) * rs;
  }
}

extern "C" void kernel_launch(void* const* d_in, const int* in_sizes, int n_in,
                              void* d_out, int out_size, void* d_ws, size_t ws_size,
                              hipStream_t stream) {
  const float* x    = (const float*)d_in[0];
  const float* wk   = (const float*)d_in[1];
  const float* wq   = (const float*)d_in[2];
  const float* fcqw = (const float*)d_in[3];
  const float* fcw  = (const float*)d_in[4];
  const float* fcb  = (const float*)d_in[5];
  const float* ag   = (const float*)d_in[6];
  const float* abt  = (const float*)d_in[7];
  const float* w1   = (const float*)d_in[8];
  const float* b1   = (const float*)d_in[9];
  const float* w2   = (const float*)d_in[10];
  const float* b2   = (const float*)d_in[11];
  const float* fg   = (const float*)d_in[12];
  const float* fb   = (const float*)d_in[13];
  float* out = (float*)d_out;

  char* p = (char*)d_ws;
  unsigned short* v_ws = (unsigned short*)p; p += (size_t)B * D * L * 2;  // bf16 v1
  float* m    = (float*)p;  p += (size_t)B * L * 4;
  float* r    = (float*)p;  p += (size_t)B * L * 4;
  float* sc   = (float*)p;  p += (size_t)B * L * 4;
  float* S1p  = (float*)p;  p += (size_t)B * 32 * D * 4;
  float* S2p  = (float*)p;  p += (size_t)B * 32 * D * 4;
  float* gw   = (float*)p;  p += (size_t)B * D * 4;
  float* A1   = (float*)p;  p += (size_t)B * D * 4;
  float* A2   = (float*)p;  p += (size_t)B * D * 4;
  float* fcqv = (float*)p;  p += (size_t)B * D * 4;
  float* sk0  = (float*)p;  p += (size_t)B * D * 4;
  float* sk1  = (float*)p;  p += (size_t)B * D * 4;
  float* Gg   = (float*)p;  p += (size_t)B * 4;
  unsigned short* w1b = (unsigned short*)p; p += (size_t)H * D * 2;
  unsigned short* w2b = (unsigned short*)p; p += (size_t)D * H * 2;

  // layer-1 FFN weights never needed (its output v is dead in the reference)
  k_convw<<<256, 256, 0, stream>>>(w1, w2, w1b, w2b);

  // ---- layer 0 ----
  k_pass1<<<B * 32, 512, 0, stream>>>(x, m, r, S1p, S2p);
  k_qproj<<<B, 256, 0, stream>>>(S1p, S2p, ag, abt, wq, wk, gw, Gg);
  k_scores<<<B * 8, 512, 0, stream>>>(x, m, r, gw, Gg, sc);
  k_redw<<<B * 16, 256, 0, stream>>>(x, m, r, sc, A1, A2);
  k_skip<<<B, 256, 0, stream>>>(A1, A2, ag, abt, fcw, fcb, fcqw, sk0, fcqv);
  // FFN (layer 0 only) + bf16 v1 write + fused layer-1 pass1 tail
  k_ffn<<<B * (L / MT), 512, 0, stream>>>(x, v_ws, fcqv, w1b, b1, w2b, b2,
                                          fg, fb, m, r, S1p, S2p);

  // ---- layer 1 (pass1 fused; v1 is bf16) ----
  k_qproj<<<B, 256, 0, stream>>>(S1p, S2p, ag + D, abt + D,
                                 wq + (size_t)KP * 2 * D, wk + (size_t)KP * D,
                                 gw, Gg);
  k_scores_bf<<<B * 4, 512, 0, stream>>>(v_ws, m, r, gw, Gg, sc);
  k_redw_bf<<<B * 16, 256, 0, stream>>>(v_ws, m, r, sc, A1, A2);
  k_skip<<<B, 256, 0, stream>>>(A1, A2, ag + D, abt + D,
                                fcw + (size_t)D * 2 * D, fcb + D,
                                fcqw + (size_t)D * D, sk1, fcqv);

  k_bn<<<1, 256, 0, stream>>>(sk0, sk1, out);
}